// Round 11
// baseline (444.870 us; speedup 1.0000x reference)
//
#include <hip/hip_runtime.h>
#include <math.h>

typedef unsigned long long ull;
typedef __attribute__((ext_vector_type(8))) short short8v;   // 8 bf16 in 4 VGPRs
typedef __attribute__((ext_vector_type(4))) float float4v;

#define NB   8
#define NTOK 256
#define CIN  256
#define NP   16384
#define NCO  512
#define HW64 4096
#define OHW  1024
#define NS   64
#define EPS  1e-6f
#define KC   2304   // 9*256 conv K
#define NKC  72     // KC/32

// ---------------- workspace layout (float offsets) ----------------
constexpr size_t OFF_SUMS = 0;                                   // cntmat(int) -> xmap packed (in-place map_gemm)
constexpr size_t OFF_CNT  = OFF_SUMS + (size_t)NB*HW64*CIN;
constexpr size_t OFF_AMAT = OFF_CNT  + (size_t)NB*HW64;          // f32, consumed directly by ssum (AF=1)
constexpr size_t OFF_ALLW = OFF_AMAT + (size_t)NB*NTOK*OHW;      // (unused now, kept for layout)
constexpr size_t OFF_DMAX = OFF_ALLW + (size_t)NB*NS;
constexpr size_t OFF_MAXW = OFF_DMAX + NB;
constexpr size_t ZERO_END = OFF_MAXW + NB;
constexpr size_t OFF_WT   = ZERO_END;                            // frag-major weights
constexpr size_t OFF_SKWT = OFF_WT   + (size_t)KC*NCO;
constexpr size_t OFF_Y    = OFF_SKWT + (size_t)CIN*NCO;          // yT packed (conv); after ssum: XTOKPK alias
constexpr size_t OFF_C2   = OFF_Y    + (size_t)NB*OHW*NCO;
constexpr size_t OFF_WSUM = OFF_C2   + (size_t)NB*NTOK*NCO;
constexpr size_t OFF_XSKIP= OFF_WSUM + (size_t)NB*NTOK;
constexpr size_t OFF_XTOK = OFF_XSKIP+ (size_t)NB*NTOK*NCO;
constexpr size_t OFF_XPK  = OFF_XTOK + (size_t)NB*NTOK*NCO;
constexpr size_t OFF_WEXP = OFF_XPK  + (size_t)NB*NTOK*NCO;
constexpr size_t OFF_SQ   = OFF_WEXP + (size_t)NB*NTOK;
constexpr size_t OFF_DIST = OFF_SQ   + (size_t)NB*NTOK;
constexpr size_t OFF_DENS = OFF_DIST + (size_t)NB*NTOK*NTOK;     // (unused)
constexpr size_t OFF_SCORE= OFF_DENS + (size_t)NB*NTOK;          // (unused)
constexpr size_t OFF_IND  = OFF_SCORE+ (size_t)NB*NTOK;          // (unused)
constexpr size_t OFF_IDXCL= OFF_IND  + (size_t)NB*NS;
constexpr size_t OFF_NORMW= OFF_IDXCL+ (size_t)NB*NTOK;
constexpr size_t OFF_AWBUF= OFF_NORMW+ (size_t)NB*NTOK;
constexpr size_t OFF_XTPK = OFF_AWBUF+ (size_t)NB*NP;
constexpr size_t OFF_XTOKPK= OFF_Y;

__device__ __forceinline__ unsigned pack_hl(float x) {
    unsigned u = __float_as_uint(x);
    unsigned t = u + 0x7fffu + ((u >> 16) & 1u);
    unsigned hibits = t & 0xffff0000u;
    float lo = x - __uint_as_float(hibits);
    unsigned ul = __float_as_uint(lo);
    unsigned lt = ul + 0x7fffu + ((ul >> 16) & 1u);
    return hibits | (lt >> 16);
}
__device__ __forceinline__ unsigned f2bf(float f) {   // RNE bf16 (top 16 bits)
    unsigned u = __float_as_uint(f);
    return (u + 0x7fffu + ((u >> 16) & 1u)) >> 16;
}
__device__ __forceinline__ unsigned hp2(unsigned w0, unsigned w1) {
    return __builtin_amdgcn_perm(w1, w0, 0x07060302u);
}
__device__ __forceinline__ unsigned lp2(unsigned w0, unsigned w1) {
    return __builtin_amdgcn_perm(w1, w0, 0x05040100u);
}

// ---------------- histogram ----------------
__global__ void hist(const float* __restrict__ loc, const int* __restrict__ idxagg,
                     const float* __restrict__ aggw,
                     int* __restrict__ cntmat, float* __restrict__ cnt,
                     float* __restrict__ amat) {
    int bp = blockIdx.x*256 + threadIdx.x;
    int b  = bp >> 14;
    float lx = loc[2*bp+0], ly = loc[2*bp+1];
    lx = fminf(fmaxf(lx, -1.f), 1.f);
    ly = fminf(fmaxf(ly, -1.f), 1.f);
    int px = (int)rintf((lx + 1.f)*32.f - 0.5f); px = min(max(px,0),63);
    int py = (int)rintf((ly + 1.f)*32.f - 0.5f); py = min(max(py,0),63);
    int cell = py*64 + px;
    int tok = idxagg[bp];
    atomicAdd(&cntmat[((size_t)(b*HW64 + cell))*NTOK + tok], 1);
    atomicAdd(&cnt[b*HW64 + cell], 1.0f);
    int qx = (int)rintf((lx + 1.f)*16.f - 0.5f); qx = min(max(qx,0),31);
    int qy = (int)rintf((ly + 1.f)*16.f - 0.5f); qy = min(max(qy,0),31);
    atomicAdd(&amat[((size_t)(b*NTOK + tok))*OHW + qy*32 + qx], aggw[bp]);
}

// x -> xtpk[b][cin][tok] (transposed, packed) AND xpk[b][tok][cin] (straight, packed)
__global__ void xpack_both(const float* __restrict__ x, unsigned* __restrict__ xtpk,
                           unsigned* __restrict__ xpk) {
    int id = blockIdx.x*256 + threadIdx.x;   // 8*256*256, tok fastest
    int tok = id & 255, cin = (id >> 8) & 255, b = id >> 16;
    unsigned pk = pack_hl(x[((size_t)(b*NTOK + tok))*CIN + cin]);
    xtpk[id] = pk;
    xpk[((size_t)(b*NTOK + tok))*CIN + cin] = pk;
}

// weights in MFMA-fragment order: wtf[(((mt*72+kc)*4+f)*2+h)*64+lane] (uint4 = 8 bf16)
__global__ void wtrans(const float* __restrict__ convw, uint4* __restrict__ wtf) {
    int tid = blockIdx.x*256 + threadIdx.x;   // 294912
    int lane = tid & 63;
    int r1 = tid >> 6;
    int h = r1 & 1;
    int r2 = r1 >> 1;
    int f = r2 & 3;
    int r3 = r2 >> 2;
    int kc = r3 % NKC, mt = r3 / NKC;
    int cout = mt*64 + f*16 + (lane & 15);
    int kb = kc*32 + (lane >> 4)*8;
    unsigned s[8];
    #pragma unroll
    for (int j = 0; j < 8; ++j) {
        int k = kb + j;
        int grp = k >> 8, cin = k & 255;
        unsigned w = pack_hl(convw[(size_t)cout*KC + cin*9 + grp]);
        s[j] = h ? (w & 0xffffu) : (w >> 16);
    }
    uint4 o;
    o.x = s[0] | (s[1]<<16); o.y = s[2] | (s[3]<<16);
    o.z = s[4] | (s[5]<<16); o.w = s[6] | (s[7]<<16);
    wtf[tid] = o;
}

__global__ void pack4(const float4* __restrict__ src, uint4* __restrict__ dst) {
    size_t i = (size_t)blockIdx.x*256 + threadIdx.x;
    float4 v = src[i];
    uint4 o;
    o.x = pack_hl(v.x); o.y = pack_hl(v.y); o.z = pack_hl(v.z); o.w = pack_hl(v.w);
    dst[i] = o;
}

// ---------------- map_gemm: x_map = (cntmat @ x)/(cnt+eps) -> packed uint IN PLACE ----------------
__launch_bounds__(512)
__global__ void map_gemm(const int* __restrict__ A, const unsigned* __restrict__ B,
                         const float* __restrict__ cnt, unsigned* __restrict__ xmapu) {
    __shared__ __align__(16) unsigned short Ah[4096];            // 128 x 32
    __shared__ __align__(16) unsigned short Bh[8192], Bl[8192];  // 256 x 32
    int z = blockIdx.z, m0 = blockIdx.y*128;
    const int* Ab = A + ((size_t)z*HW64 + m0)*NTOK;
    const unsigned* Bb = B + (size_t)z*CIN*NTOK;
    int t = threadIdx.x, lane = t & 63;
    int w = t >> 6;
    int wm = w >> 2, wn = w & 3;
    int l15 = lane & 15, l4 = lane >> 4;
    int rowA = t & 127, kgA = t >> 7;
    int rowB = t & 255, kgB0 = (t >> 8)*2;
    const int* arow = Ab + (size_t)rowA*NTOK + kgA*8;
    const unsigned* brow = Bb + (size_t)rowB*NTOK + kgB0*8;
    int wbA = (rowA>>4)*512 + kgA*128 + (rowA&15)*8;
    int wbB = (rowB>>4)*512 + kgB0*128 + (rowB&15)*8;

    float4v acc[4][4] = {};
    int4 ia0, ia1;
    uint4 rb[2][2];
    auto loadA = [&](int kc) {
        const int* p = arow + kc*32;
        ia0 = *(const int4*)p; ia1 = *(const int4*)(p + 4);
    };
    auto loadB = [&](int kc) {
        #pragma unroll
        for (int s = 0; s < 2; ++s) {
            const unsigned* p = brow + kc*32 + s*8;
            rb[s][0] = *(const uint4*)p; rb[s][1] = *(const uint4*)(p + 4);
        }
    };
    loadA(0); loadB(0);

    for (int kc = 0; kc < 8; ++kc) {
        __syncthreads();
        uint4 h, l;
        h.x = f2bf((float)ia0.x) | (f2bf((float)ia0.y) << 16);
        h.y = f2bf((float)ia0.z) | (f2bf((float)ia0.w) << 16);
        h.z = f2bf((float)ia1.x) | (f2bf((float)ia1.y) << 16);
        h.w = f2bf((float)ia1.z) | (f2bf((float)ia1.w) << 16);
        *(uint4*)&Ah[wbA] = h;
        #pragma unroll
        for (int s = 0; s < 2; ++s) {
            uint4 u0 = rb[s][0], u1 = rb[s][1];
            h.x=hp2(u0.x,u0.y); h.y=hp2(u0.z,u0.w); h.z=hp2(u1.x,u1.y); h.w=hp2(u1.z,u1.w);
            l.x=lp2(u0.x,u0.y); l.y=lp2(u0.z,u0.w); l.z=lp2(u1.x,u1.y); l.w=lp2(u1.z,u1.w);
            *(uint4*)&Bh[wbB + s*128] = h; *(uint4*)&Bl[wbB + s*128] = l;
        }
        __syncthreads();
        if (kc < 7) { loadA(kc+1); loadB(kc+1); }

        short8v bh[4], bl[4];
        #pragma unroll
        for (int q = 0; q < 4; ++q) {
            int off = (wn*4 + q)*512 + l4*128 + l15*8;
            bh[q] = *(const short8v*)&Bh[off];
            bl[q] = *(const short8v*)&Bl[off];
        }
        #pragma unroll
        for (int p = 0; p < 4; ++p) {
            int off = (wm*4 + p)*512 + l4*128 + l15*8;
            short8v ah = *(const short8v*)&Ah[off];
            #pragma unroll
            for (int q = 0; q < 4; ++q) {
                acc[p][q] = __builtin_amdgcn_mfma_f32_16x16x32_bf16(ah, bh[q], acc[p][q], 0, 0, 0);
                acc[p][q] = __builtin_amdgcn_mfma_f32_16x16x32_bf16(ah, bl[q], acc[p][q], 0, 0, 0);
            }
        }
    }

    const float* cntb = cnt + (size_t)z*HW64;
    #pragma unroll
    for (int p = 0; p < 4; ++p) {
        int mb = m0 + wm*64 + p*16 + l4*4;
        #pragma unroll
        for (int q = 0; q < 4; ++q) {
            int n = wn*64 + q*16 + l15;
            #pragma unroll
            for (int r = 0; r < 4; ++r) {
                float v = acc[p][q][r] / (cntb[mb + r] + EPS);
                xmapu[((size_t)z*HW64 + mb + r)*CIN + n] = pack_hl(v);
            }
        }
    }
}

// ---------------- conv: 128(pos)x64(cout), 2D grid (R7), DEPTH-2 A prefetch ----------------
__launch_bounds__(256)
__global__ void conv_gemm(const unsigned* __restrict__ xmap, const uint4* __restrict__ wtf,
                          const float* __restrict__ convb, unsigned* __restrict__ ytp) {
    __shared__ __align__(16) unsigned short Ahi[2][4096], Alo[2][4096];  // dbuf, 128 pos x 32 k
    int n0 = blockIdx.x * 128;          // pos tile (64)
    int mt = blockIdx.y;                // cout tile (8)
    int m0 = mt * 64;
    int t = threadIdx.x;
    int lane = t & 63, wid = t >> 6;
    int wm = wid >> 1, wn = wid & 1;    // wave: 64 pos x 32 cout
    int l15 = lane & 15, l4 = lane >> 4;

    int rowL = t & 127, kg = t >> 7;
    int posG = n0 + rowL;
    int bb = posG >> 10, rem = posG & 1023;
    int oy = rem >> 5, ox = rem & 31;

    int wbA0 = (rowL>>4)*512 + kg*128 + (rowL&15)*8;
    int wbA1 = wbA0 + 256;

    float4v acc[4][2] = {};
    uint4 aA0,aA1,aA2,aA3;   // reg set A
    uint4 aB0,aB1,aB2,aB3;   // reg set B

    auto addrA = [&](int kc, int* ok) -> const unsigned* {
        int grp = kc >> 3;
        int ky = grp/3, kx = grp - 3*ky;
        int iy = 2*oy - 1 + ky, ix = 2*ox - 1 + kx;
        *ok = ((unsigned)iy < 64u) && ((unsigned)ix < 64u);
        return xmap + ((((size_t)bb*64 + iy)*64 + ix)*256 + (kc&7)*32 + kg*8);
    };
    auto loadA_A = [&](int kc) {
        int ok; const unsigned* ap = addrA(kc, &ok);
        if (ok) {
            aA0 = *(const uint4*)ap;       aA1 = *(const uint4*)(ap + 4);
            aA2 = *(const uint4*)(ap + 16); aA3 = *(const uint4*)(ap + 20);
        } else { aA0 = make_uint4(0,0,0,0); aA1 = aA0; aA2 = aA0; aA3 = aA0; }
    };
    auto loadA_B = [&](int kc) {
        int ok; const unsigned* ap = addrA(kc, &ok);
        if (ok) {
            aB0 = *(const uint4*)ap;       aB1 = *(const uint4*)(ap + 4);
            aB2 = *(const uint4*)(ap + 16); aB3 = *(const uint4*)(ap + 20);
        } else { aB0 = make_uint4(0,0,0,0); aB1 = aB0; aB2 = aB0; aB3 = aB0; }
    };
    auto repack_A = [&](int buf) {
        uint4 h, l;
        h.x=hp2(aA0.x,aA0.y); h.y=hp2(aA0.z,aA0.w); h.z=hp2(aA1.x,aA1.y); h.w=hp2(aA1.z,aA1.w);
        l.x=lp2(aA0.x,aA0.y); l.y=lp2(aA0.z,aA0.w); l.z=lp2(aA1.x,aA1.y); l.w=lp2(aA1.z,aA1.w);
        *(uint4*)&Ahi[buf][wbA0] = h; *(uint4*)&Alo[buf][wbA0] = l;
        h.x=hp2(aA2.x,aA2.y); h.y=hp2(aA2.z,aA2.w); h.z=hp2(aA3.x,aA3.y); h.w=hp2(aA3.z,aA3.w);
        l.x=lp2(aA2.x,aA2.y); l.y=lp2(aA2.z,aA2.w); l.z=lp2(aA3.x,aA3.y); l.w=lp2(aA3.z,aA3.w);
        *(uint4*)&Ahi[buf][wbA1] = h; *(uint4*)&Alo[buf][wbA1] = l;
    };
    auto repack_B = [&](int buf) {
        uint4 h, l;
        h.x=hp2(aB0.x,aB0.y); h.y=hp2(aB0.z,aB0.w); h.z=hp2(aB1.x,aB1.y); h.w=hp2(aB1.z,aB1.w);
        l.x=lp2(aB0.x,aB0.y); l.y=lp2(aB0.z,aB0.w); l.z=lp2(aB1.x,aB1.y); l.w=lp2(aB1.z,aB1.w);
        *(uint4*)&Ahi[buf][wbA0] = h; *(uint4*)&Alo[buf][wbA0] = l;
        h.x=hp2(aB2.x,aB2.y); h.y=hp2(aB2.z,aB2.w); h.z=hp2(aB3.x,aB3.y); h.w=hp2(aB3.z,aB3.w);
        l.x=lp2(aB2.x,aB2.y); l.y=lp2(aB2.z,aB2.w); l.z=lp2(aB3.x,aB3.y); l.w=lp2(aB3.z,aB3.w);
        *(uint4*)&Ahi[buf][wbA1] = h; *(uint4*)&Alo[buf][wbA1] = l;
    };
    const uint4* wbase = wtf + ((size_t)(((mt*NKC)*4 + wn*2)*2))*64 + lane;

    short8v bhc[2], blc[2], bhn[2], bln[2];
    #pragma unroll
    for (int q = 0; q < 2; ++q) {
        bhc[q] = *(const short8v*)(wbase + q*128);
        blc[q] = *(const short8v*)(wbase + q*128 + 64);
    }
    // prologue: kc=0 staged via set B; kc=1 in flight via set A
    loadA_B(0);
    repack_B(0);
    loadA_A(1);
    __syncthreads();
    int cur = 0;

    #define CONV_MFMA_BLOCK                                                            \
        _Pragma("unroll")                                                              \
        for (int p = 0; p < 4; ++p) {                                                  \
            int off = (wm*4 + p)*512 + l4*128 + l15*8;                                 \
            short8v ah = *(const short8v*)&Ahi[cur][off];                              \
            short8v al = *(const short8v*)&Alo[cur][off];                              \
            _Pragma("unroll")                                                          \
            for (int q = 0; q < 2; ++q) {                                              \
                acc[p][q] = __builtin_amdgcn_mfma_f32_16x16x32_bf16(ah, bhc[q], acc[p][q], 0, 0, 0); \
                acc[p][q] = __builtin_amdgcn_mfma_f32_16x16x32_bf16(ah, blc[q], acc[p][q], 0, 0, 0); \
                acc[p][q] = __builtin_amdgcn_mfma_f32_16x16x32_bf16(al, bhc[q], acc[p][q], 0, 0, 0); \
            }                                                                          \
        }

    for (int kc = 0; kc < NKC; kc += 2) {
        // even iter: LDS[cur] = kc; set A holds kc+1 (in flight since prev iter)
        if (kc + 2 < NKC) loadA_B(kc + 2);
        {
            const uint4* wb = wbase + (size_t)(kc+1)*512;
            #pragma unroll
            for (int q = 0; q < 2; ++q) {
                bhn[q] = *(const short8v*)(wb + q*128);
                bln[q] = *(const short8v*)(wb + q*128 + 64);
            }
        }
        CONV_MFMA_BLOCK
        repack_A(cur ^ 1);    // waits vmcnt for set-A loads issued a full iteration ago
        #pragma unroll
        for (int q = 0; q < 2; ++q) { bhc[q] = bhn[q]; blc[q] = bln[q]; }
        __syncthreads();
        cur ^= 1;

        // odd iter k1 = kc+1: LDS[cur] = k1; set B holds k1+1 (if any)
        int k1 = kc + 1;
        if (k1 + 2 < NKC) loadA_A(k1 + 2);
        if (k1 + 1 < NKC) {
            const uint4* wb = wbase + (size_t)(k1+1)*512;
            #pragma unroll
            for (int q = 0; q < 2; ++q) {
                bhn[q] = *(const short8v*)(wb + q*128);
                bln[q] = *(const short8v*)(wb + q*128 + 64);
            }
        }
        CONV_MFMA_BLOCK
        if (k1 + 1 < NKC) {
            repack_B(cur ^ 1);
            #pragma unroll
            for (int q = 0; q < 2; ++q) { bhc[q] = bhn[q]; blc[q] = bln[q]; }
        }
        __syncthreads();
        cur ^= 1;
    }
    #undef CONV_MFMA_BLOCK

    int bbk = n0 >> 10;
    int pos0 = (n0 & 1023) + wm*64;
    #pragma unroll
    for (int p = 0; p < 4; ++p) {
        int posb = pos0 + p*16 + l4*4;
        #pragma unroll
        for (int q = 0; q < 2; ++q) {
            int col = m0 + wn*32 + q*16 + l15;
            float bv = convb[col];
            uint4 o;
            o.x = pack_hl(acc[p][q][0] + bv);
            o.y = pack_hl(acc[p][q][1] + bv);
            o.z = pack_hl(acc[p][q][2] + bv);
            o.w = pack_hl(acc[p][q][3] + bv);
            *(uint4*)&ytp[((size_t)(bbk*NCO + col))*OHW + posb] = o;
        }
    }
}

// ---------------- generic split-bf16 MFMA GEMM, TM x TN tile ----------------
template<int MODE, int TM, int TN, int AF>
__launch_bounds__(256)
__global__ void gemm_pk(const void* __restrict__ Av, const unsigned* __restrict__ B,
                        float* __restrict__ C, int K, int N,
                        long sA, long sB, long sC,
                        const float* __restrict__ aux, unsigned* __restrict__ dmaxU) {
    constexpr int NA = TM/64, NBs = TN/64;
    constexpr int WSM = TM/64;
    constexpr int WSN = 4/WSM;
    constexpr int TWM = TM/WSM, TWN = TN/WSN;
    constexpr int P = TWM/16, Q = TWN/16;
    __shared__ __align__(16) unsigned short Ahi[TM*32], Alo[TM*32];
    __shared__ __align__(16) unsigned short Bhi[TN*32], Blo[TN*32];
    int z = blockIdx.z;
    const unsigned* Ab = (const unsigned*)Av + (size_t)z*sA;
    const unsigned* Bb = B + (size_t)z*sB;
    float* Cb = C + (size_t)z*sC;
    int n0 = blockIdx.x*TN, m0 = blockIdx.y*TM;
    int t = threadIdx.x;
    int lane = t & 63, wid = t >> 6;
    int wm = (WSM==2) ? (wid >> 1) : 0;
    int wn = (WSM==2) ? (wid & 1)  : wid;
    int l15 = lane & 15, l4 = lane >> 4;

    int rowA = t & (TM-1), kgA = t / TM;
    int rowB = t & (TN-1), kgB = t / TN;
    const unsigned* arow = Ab + (size_t)(m0 + rowA)*K + kgA*8;
    const unsigned* brw  = Bb + (size_t)(n0 + rowB)*K + kgB*8;
    int wbA = (rowA>>4)*512 + kgA*128 + (rowA&15)*8;
    int wbB = (rowB>>4)*512 + kgB*128 + (rowB&15)*8;

    float4v acc[P][Q] = {};
    uint4 ra[NA][2], rb[NBs][2];
    auto loadA = [&](int kc) {
        #pragma unroll
        for (int s = 0; s < NA; ++s) {
            const unsigned* p = arow + (size_t)kc*32 + s*16;
            ra[s][0] = *(const uint4*)p; ra[s][1] = *(const uint4*)(p + 4);
        }
    };
    auto loadB = [&](int kc) {
        #pragma unroll
        for (int s = 0; s < NBs; ++s) {
            const unsigned* p = brw + (size_t)kc*32 + s*16;
            rb[s][0] = *(const uint4*)p; rb[s][1] = *(const uint4*)(p + 4);
        }
    };
    loadA(0); loadB(0);
    int nkc = K >> 5;

    for (int kc = 0; kc < nkc; ++kc) {
        __syncthreads();
        uint4 h, l;
        #pragma unroll
        for (int s = 0; s < NA; ++s) {
            uint4 u0 = ra[s][0], u1 = ra[s][1];
            if (AF == 0) {
                h.x=hp2(u0.x,u0.y); h.y=hp2(u0.z,u0.w); h.z=hp2(u1.x,u1.y); h.w=hp2(u1.z,u1.w);
                l.x=lp2(u0.x,u0.y); l.y=lp2(u0.z,u0.w); l.z=lp2(u1.x,u1.y); l.w=lp2(u1.z,u1.w);
            } else {
                unsigned pk0 = pack_hl(__uint_as_float(u0.x)), pk1 = pack_hl(__uint_as_float(u0.y));
                unsigned pk2 = pack_hl(__uint_as_float(u0.z)), pk3 = pack_hl(__uint_as_float(u0.w));
                unsigned pk4 = pack_hl(__uint_as_float(u1.x)), pk5 = pack_hl(__uint_as_float(u1.y));
                unsigned pk6 = pack_hl(__uint_as_float(u1.z)), pk7 = pack_hl(__uint_as_float(u1.w));
                h.x = (pk0>>16) | (pk1 & 0xffff0000u); h.y = (pk2>>16) | (pk3 & 0xffff0000u);
                h.z = (pk4>>16) | (pk5 & 0xffff0000u); h.w = (pk6>>16) | (pk7 & 0xffff0000u);
                l.x = (pk0&0xffffu) | (pk1<<16); l.y = (pk2&0xffffu) | (pk3<<16);
                l.z = (pk4&0xffffu) | (pk5<<16); l.w = (pk6&0xffffu) | (pk7<<16);
            }
            *(uint4*)&Ahi[wbA + s*256] = h; *(uint4*)&Alo[wbA + s*256] = l;
        }
        #pragma unroll
        for (int s = 0; s < NBs; ++s) {
            uint4 u0 = rb[s][0], u1 = rb[s][1];
            h.x=hp2(u0.x,u0.y); h.y=hp2(u0.z,u0.w); h.z=hp2(u1.x,u1.y); h.w=hp2(u1.z,u1.w);
            l.x=lp2(u0.x,u0.y); l.y=lp2(u0.z,u0.w); l.z=lp2(u1.x,u1.y); l.w=lp2(u1.z,u1.w);
            *(uint4*)&Bhi[wbB + s*256] = h; *(uint4*)&Blo[wbB + s*256] = l;
        }
        __syncthreads();
        if (kc + 1 < nkc) { loadA(kc+1); loadB(kc+1); }

        short8v bh[Q], bl[Q];
        #pragma unroll
        for (int q = 0; q < Q; ++q) {
            int off = (wn*Q + q)*512 + l4*128 + l15*8;
            bh[q] = *(const short8v*)&Bhi[off];
            bl[q] = *(const short8v*)&Blo[off];
        }
        #pragma unroll
        for (int p = 0; p < P; ++p) {
            int off = (wm*P + p)*512 + l4*128 + l15*8;
            short8v ah = *(const short8v*)&Ahi[off];
            short8v al = *(const short8v*)&Alo[off];
            #pragma unroll
            for (int q = 0; q < Q; ++q) {
                acc[p][q] = __builtin_amdgcn_mfma_f32_16x16x32_bf16(ah, bh[q], acc[p][q], 0, 0, 0);
                acc[p][q] = __builtin_amdgcn_mfma_f32_16x16x32_bf16(ah, bl[q], acc[p][q], 0, 0, 0);
                acc[p][q] = __builtin_amdgcn_mfma_f32_16x16x32_bf16(al, bh[q], acc[p][q], 0, 0, 0);
            }
        }
    }

    if (MODE == 0) {
        #pragma unroll
        for (int p = 0; p < P; ++p) {
            int mb = m0 + wm*TWM + p*16 + l4*4;
            #pragma unroll
            for (int q = 0; q < Q; ++q) {
                int n = n0 + wn*TWN + q*16 + l15;
                #pragma unroll
                for (int r = 0; r < 4; ++r)
                    Cb[(size_t)(mb + r)*N + n] = acc[p][q][r];
            }
        }
    } else {
        const float inv = 1.0f / sqrtf(512.0f);
        const float* sqb = aux + (size_t)z*NTOK;
        float tmax = 0.f;
        #pragma unroll
        for (int p = 0; p < P; ++p) {
            int mb = m0 + wm*TWM + p*16 + l4*4;
            #pragma unroll
            for (int q = 0; q < Q; ++q) {
                int n = n0 + wn*TWN + q*16 + l15;
                float sn = sqb[n];
                #pragma unroll
                for (int r = 0; r < 4; ++r) {
                    float d2 = sqb[mb + r] + sn - 2.0f*acc[p][q][r];
                    float d = sqrtf(fmaxf(d2, 0.0f)) * inv;
                    Cb[(size_t)(mb + r)*N + n] = d;
                    tmax = fmaxf(tmax, d);
                }
            }
        }
        __shared__ float redm[4];
        #pragma unroll
        for (int off = 32; off; off >>= 1) tmax = fmaxf(tmax, __shfl_xor(tmax, off, 64));
        if (lane == 0) redm[wid] = tmax;
        __syncthreads();
        if (t == 0) {
            float m = fmaxf(fmaxf(redm[0], redm[1]), fmaxf(redm[2], redm[3]));
            atomicMax(dmaxU + z, __float_as_uint(m));
        }
    }
}

// ---------------- remaining pipeline ----------------
__global__ void wsum_rows(const float* __restrict__ amat, float* __restrict__ wsum) {
    int row = blockIdx.x*4 + (threadIdx.x >> 6);
    int lane = threadIdx.x & 63;
    const float* ar = amat + (size_t)row*OHW;
    float s = 0.f;
    #pragma unroll
    for (int r = 0; r < 16; ++r) s += ar[lane + 64*r];
    #pragma unroll
    for (int off = 32; off; off >>= 1) s += __shfl_xor(s, off, 64);
    if (lane == 0) wsum[row] = s;
}

__device__ __forceinline__ float block_sum256(float v, float* red) {
    #pragma unroll
    for (int off = 32; off; off >>= 1) v += __shfl_xor(v, off, 64);
    __syncthreads();
    if ((threadIdx.x & 63) == 0) red[threadIdx.x >> 6] = v;
    __syncthreads();
    return red[0] + red[1] + red[2] + red[3];
}

__global__ void ln_conf(const float* __restrict__ C2, const float* __restrict__ wsum,
                        const float* __restrict__ xskip, const float* __restrict__ g,
                        const float* __restrict__ be, const float* __restrict__ confw,
                        const float* __restrict__ confb, float* __restrict__ xtok,
                        unsigned* __restrict__ xtokpk,
                        float* __restrict__ wexp, float* __restrict__ sqv) {
    __shared__ float red[4];
    int row = blockIdx.x, t = threadIdx.x;
    float ws = wsum[row] + EPS;
    size_t base = (size_t)row*NCO;
    float v0 = C2[base + t]       / ws + xskip[base + t];
    float v1 = C2[base + t + 256] / ws + xskip[base + t + 256];
    float mu  = block_sum256(v0 + v1, red) / 512.0f;
    float d0 = v0 - mu, d1 = v1 - mu;
    float var = block_sum256(d0*d0 + d1*d1, red) / 512.0f;
    float sv = sqrtf(var + 1e-5f);
    float x0 = d0/sv * g[t]       + be[t];
    float x1 = d1/sv * g[t + 256] + be[t + 256];
    xtok[base + t] = x0;
    xtok[base + t + 256] = x1;
    xtokpk[base + t] = pack_hl(x0);
    xtokpk[base + t + 256] = pack_hl(x1);
    float cs = block_sum256(x0*confw[t] + x1*confw[t + 256], red);
    float qs = block_sum256(x0*x0 + x1*x1, red);
    if (t == 0) {
        wexp[row] = expf(cs + confb[0]);
        sqv[row]  = qs;
    }
}

// ---------------- fused per-batch clustering tail (replaces 7 kernels) ----------------
// grid(8), 256 threads. dens/score/ind/idxcl/allw in LDS; writes idxcl + normw to global.
__launch_bounds__(256)
__global__ void cluster_tail(const float* __restrict__ dist, const unsigned* __restrict__ dmaxU,
                             const float* __restrict__ wexp,
                             int* __restrict__ idxcl_g, float* __restrict__ normw_g) {
    __shared__ float densL[NTOK], scoreL[NTOK], allwL[NS];
    __shared__ int indL[NS], idxclL[NTOK];
    int b = blockIdx.x, t = threadIdx.x;
    int lane = t & 63, w = t >> 6;
    const float* db = dist + (size_t)b*NTOK*NTOK;
    const float* we = wexp + (size_t)b*NTOK;

    // stage 1: density (one wave per row, 64 rows/wave)
    for (int r = w; r < NTOK; r += 4) {
        const float* dr = db + (size_t)r*NTOK;
        float v0 = dr[lane], v1 = dr[lane+64], v2 = dr[lane+128], v3 = dr[lane+192];
        float acc = 0.f;
        #pragma unroll
        for (int it = 0; it < 5; ++it) {
            float lm = fminf(fminf(v0, v1), fminf(v2, v3));
            float gm = lm;
            #pragma unroll
            for (int off = 32; off; off >>= 1) gm = fminf(gm, __shfl_xor(gm, off, 64));
            acc += gm*gm;
            ull ball = __ballot(lm == gm);
            int first = __ffsll(ball) - 1;
            if (lane == first) {
                if      (v0 == gm) v0 = 1e30f;
                else if (v1 == gm) v1 = 1e30f;
                else if (v2 == gm) v2 = 1e30f;
                else               v3 = 1e30f;
            }
        }
        if (lane == 0) densL[r] = expf(-(acc/5.0f));
    }
    __syncthreads();

    // stage 2: parent_dist * density
    float dm = __uint_as_float(dmaxU[b]);
    for (int r = w; r < NTOK; r += 4) {
        const float* dr = db + (size_t)r*NTOK;
        float di = densL[r];
        float pd = dm;
        #pragma unroll
        for (int c = 0; c < 4; ++c) {
            int j = lane + 64*c;
            pd = fminf(pd, (densL[j] > di) ? dr[j] : dm);
        }
        #pragma unroll
        for (int off = 32; off; off >>= 1) pd = fminf(pd, __shfl_xor(pd, off, 64));
        if (lane == 0) scoreL[r] = pd * di;
    }
    __syncthreads();

    // stage 3: top-64 (wave 0 only), descending, lower index first on ties
    if (w == 0) {
        ull k0, k1, k2, k3;
        unsigned i0 = lane, i1 = lane+64, i2 = lane+128, i3 = lane+192;
        k0 = ((ull)(__float_as_uint(scoreL[i0]) + 1u) << 32) | (unsigned)(4095 - i0);
        k1 = ((ull)(__float_as_uint(scoreL[i1]) + 1u) << 32) | (unsigned)(4095 - i1);
        k2 = ((ull)(__float_as_uint(scoreL[i2]) + 1u) << 32) | (unsigned)(4095 - i2);
        k3 = ((ull)(__float_as_uint(scoreL[i3]) + 1u) << 32) | (unsigned)(4095 - i3);
        for (int it = 0; it < NS; ++it) {
            ull lm = k0;
            if (k1 > lm) lm = k1;
            if (k2 > lm) lm = k2;
            if (k3 > lm) lm = k3;
            ull gm = lm;
            #pragma unroll
            for (int off = 32; off; off >>= 1) {
                ull o = __shfl_xor(gm, off, 64);
                if (o > gm) gm = o;
            }
            if (lane == 0) indL[it] = 4095 - (int)(gm & 0xffffffffull);
            if      (k0 == gm) k0 = 0;
            else if (k1 == gm) k1 = 0;
            else if (k2 == gm) k2 = 0;
            else if (k3 == gm) k3 = 0;
        }
    }
    __syncthreads();

    // stage 4: assign each token to nearest center (first min over center order)
    int myc = indL[lane];
    for (int r = w; r < NTOK; r += 4) {
        float d = db[(size_t)myc*NTOK + r];
        ull key = ((ull)__float_as_uint(d) << 32) | (unsigned)lane;
        #pragma unroll
        for (int off = 32; off; off >>= 1) {
            ull o = __shfl_xor(key, off, 64);
            if (o < key) key = o;
        }
        if (lane == 0) idxclL[r] = (int)(key & 0xffffffffull);
    }
    __syncthreads();

    // stage 5: centers assign to themselves
    if (t < NS) idxclL[indL[t]] = t;
    if (t < NS) allwL[t] = 0.f;
    __syncthreads();

    // stage 6: allw accumulation (LDS atomics)
    atomicAdd(&allwL[idxclL[t]], we[t]);
    __syncthreads();

    // stage 7: normw + write-out
    normw_g[(size_t)b*NTOK + t] = we[t] / (allwL[idxclL[t]] + EPS);
    idxcl_g[(size_t)b*NTOK + t] = idxclL[t];
}

__global__ void merge_k(const float* __restrict__ xtok, const int* __restrict__ idxcl,
                        const float* __restrict__ normw, float* __restrict__ xout) {
    int row = blockIdx.x, t = threadIdx.x;
    int b = row >> 8;
    int cl = idxcl[row];
    float nw = normw[row];
    float* o = xout + ((size_t)(b*NS + cl))*NCO;
    const float* xr = xtok + (size_t)row*NCO;
    atomicAdd(&o[t],       xr[t]       * nw);
    atomicAdd(&o[t + 256], xr[t + 256] * nw);
}

__global__ void out_idx_aw(const int* __restrict__ idxagg, const float* __restrict__ aggw,
                           const int* __restrict__ idxcl, const float* __restrict__ normw,
                           float* __restrict__ dout, float* __restrict__ awbuf,
                           unsigned* __restrict__ maxw) {
    __shared__ float red[4];
    int bp = blockIdx.x*256 + threadIdx.x;
    int b = bp >> 14;
    int tok = idxagg[bp];
    int cl = idxcl[b*NTOK + tok];
    dout[(size_t)NB*NS*NCO + bp] = (float)cl;
    float aw = aggw[bp] * normw[b*NTOK + tok];
    awbuf[bp] = aw;
    float m = aw;
    #pragma unroll
    for (int off = 32; off; off >>= 1) m = fmaxf(m, __shfl_xor(m, off, 64));
    if ((threadIdx.x & 63) == 0) red[threadIdx.x >> 6] = m;
    __syncthreads();
    if (threadIdx.x == 0) {
        float mm = fmaxf(fmaxf(red[0], red[1]), fmaxf(red[2], red[3]));
        atomicMax(&maxw[b], __float_as_uint(mm));
    }
}

__global__ void aw_final(const float* __restrict__ awbuf, const float* __restrict__ maxw,
                         float* __restrict__ dout) {
    int bp = blockIdx.x*256 + threadIdx.x;
    int b = bp >> 14;
    dout[(size_t)NB*NS*NCO + (size_t)NB*NP + bp] = awbuf[bp] / maxw[b];
}

// ---------------- launch ----------------
extern "C" void kernel_launch(void* const* d_in, const int* in_sizes, int n_in,
                              void* d_out, int out_size, void* d_ws, size_t ws_size,
                              hipStream_t stream) {
    const float* x      = (const float*)d_in[0];
    const float* loc    = (const float*)d_in[1];
    const int*   idxagg = (const int*)  d_in[2];
    const float* aggw   = (const float*)d_in[3];
    const float* convw  = (const float*)d_in[7];
    const float* convb  = (const float*)d_in[8];
    const float* skipw  = (const float*)d_in[9];
    const float* lng    = (const float*)d_in[10];
    const float* lnb    = (const float*)d_in[11];
    const float* confw  = (const float*)d_in[12];
    const float* confb  = (const float*)d_in[13];

    float* ws = (float*)d_ws;
    float* dout = (float*)d_out;

    (void)hipMemsetAsync(ws, 0, ZERO_END*sizeof(float), stream);
    (void)hipMemsetAsync(dout, 0, (size_t)NB*NS*NCO*sizeof(float), stream);

    hist<<<dim3(NB*NP/256), 256, 0, stream>>>(loc, idxagg, aggw,
                                              (int*)(ws + OFF_SUMS), ws + OFF_CNT, ws + OFF_AMAT);
    xpack_both<<<dim3(NB*CIN*NTOK/256), 256, 0, stream>>>(x, (unsigned*)(ws + OFF_XTPK),
                                                          (unsigned*)(ws + OFF_XPK));
    wtrans<<<dim3(1152), 256, 0, stream>>>(convw, (uint4*)(ws + OFF_WT));
    pack4<<<dim3(CIN*NCO/1024), 256, 0, stream>>>((const float4*)skipw, (uint4*)(ws + OFF_SKWT));

    map_gemm<<<dim3(1, 32, 8), 512, 0, stream>>>((const int*)(ws + OFF_SUMS),
                                                 (const unsigned*)(ws + OFF_XTPK),
                                                 ws + OFF_CNT,
                                                 (unsigned*)(ws + OFF_SUMS));

    // conv: 2D grid (R7-proven), depth-2 A prefetch
    conv_gemm<<<dim3(64, 8), 256, 0, stream>>>((const unsigned*)(ws + OFF_SUMS),
                                               (const uint4*)(ws + OFF_WT), convb,
                                               (unsigned*)(ws + OFF_Y));

    wsum_rows<<<dim3(NB*NTOK/4), 256, 0, stream>>>(ws + OFF_AMAT, ws + OFF_WSUM);
    gemm_pk<0,64,64,1><<<dim3(8, 4, 8), 256, 0, stream>>>((const void*)(ws + OFF_AMAT),
                                                  (const unsigned*)(ws + OFF_Y),
                                                  ws + OFF_C2, OHW, NCO,
                                                  (long)NTOK*OHW, (long)NCO*OHW, (long)NTOK*NCO,
                                                  nullptr, nullptr);
    gemm_pk<0,64,64,0><<<dim3(8, 32, 1), 256, 0, stream>>>((const void*)(ws + OFF_XPK),
                                                   (const unsigned*)(ws + OFF_SKWT),
                                                   ws + OFF_XSKIP, CIN, NCO, 0, 0, 0,
                                                   nullptr, nullptr);

    ln_conf<<<dim3(NB*NTOK), 256, 0, stream>>>(ws + OFF_C2, ws + OFF_WSUM, ws + OFF_XSKIP,
                                               lng, lnb, confw, confb,
                                               ws + OFF_XTOK, (unsigned*)(ws + OFF_XTOKPK),
                                               ws + OFF_WEXP, ws + OFF_SQ);

    gemm_pk<1,64,64,0><<<dim3(4, 4, 8), 256, 0, stream>>>((const void*)(ws + OFF_XTOKPK),
                                                  (const unsigned*)(ws + OFF_XTOKPK),
                                                  ws + OFF_DIST, NCO, NTOK,
                                                  (long)NTOK*NCO, (long)NTOK*NCO, (long)NTOK*NTOK,
                                                  ws + OFF_SQ, (unsigned*)(ws + OFF_DMAX));

    cluster_tail<<<dim3(NB), 256, 0, stream>>>(ws + OFF_DIST,
                                               (const unsigned*)(ws + OFF_DMAX),
                                               ws + OFF_WEXP,
                                               (int*)(ws + OFF_IDXCL), ws + OFF_NORMW);

    merge_k<<<dim3(NB*NTOK), 256, 0, stream>>>(ws + OFF_XTOK, (const int*)(ws + OFF_IDXCL),
                                               ws + OFF_NORMW, dout);
    out_idx_aw<<<dim3(NB*NP/256), 256, 0, stream>>>(idxagg, aggw, (const int*)(ws + OFF_IDXCL),
                                                    ws + OFF_NORMW, dout, ws + OFF_AWBUF,
                                                    (unsigned*)(ws + OFF_MAXW));
    aw_final<<<dim3(NB*NP/256), 256, 0, stream>>>(ws + OFF_AWBUF, (const float*)(ws + OFF_MAXW), dout);
}

// Round 12
// 295.926 us; speedup vs baseline: 1.5033x; 1.5033x over previous
//
#include <hip/hip_runtime.h>
#include <math.h>

typedef unsigned long long ull;
typedef __attribute__((ext_vector_type(8))) short short8v;   // 8 bf16 in 4 VGPRs
typedef __attribute__((ext_vector_type(4))) float float4v;

#define NB   8
#define NTOK 256
#define CIN  256
#define NP   16384
#define NCO  512
#define HW64 4096
#define OHW  1024
#define NS   64
#define EPS  1e-6f
#define KC   2304   // 9*256 conv K
#define NKC  72     // KC/32

// ---------------- workspace layout (float offsets) ----------------
constexpr size_t OFF_SUMS = 0;                                   // cntmat(int) -> xmap packed (in-place map_gemm)
constexpr size_t OFF_CNT  = OFF_SUMS + (size_t)NB*HW64*CIN;
constexpr size_t OFF_AMAT = OFF_CNT  + (size_t)NB*HW64;          // f32, consumed directly by ssum (AF=1)
constexpr size_t OFF_ALLW = OFF_AMAT + (size_t)NB*NTOK*OHW;
constexpr size_t OFF_DMAX = OFF_ALLW + (size_t)NB*NS;
constexpr size_t OFF_MAXW = OFF_DMAX + NB;
constexpr size_t ZERO_END = OFF_MAXW + NB;
constexpr size_t OFF_WT   = ZERO_END;                            // frag-major weights
constexpr size_t OFF_SKWT = OFF_WT   + (size_t)KC*NCO;
constexpr size_t OFF_Y    = OFF_SKWT + (size_t)CIN*NCO;          // yT packed (conv); after ssum: XTOKPK alias
constexpr size_t OFF_C2   = OFF_Y    + (size_t)NB*OHW*NCO;
constexpr size_t OFF_WSUM = OFF_C2   + (size_t)NB*NTOK*NCO;
constexpr size_t OFF_XSKIP= OFF_WSUM + (size_t)NB*NTOK;
constexpr size_t OFF_XTOK = OFF_XSKIP+ (size_t)NB*NTOK*NCO;
constexpr size_t OFF_XPK  = OFF_XTOK + (size_t)NB*NTOK*NCO;
constexpr size_t OFF_WEXP = OFF_XPK  + (size_t)NB*NTOK*NCO;
constexpr size_t OFF_SQ   = OFF_WEXP + (size_t)NB*NTOK;
constexpr size_t OFF_DIST = OFF_SQ   + (size_t)NB*NTOK;
constexpr size_t OFF_DENS = OFF_DIST + (size_t)NB*NTOK*NTOK;
constexpr size_t OFF_SCORE= OFF_DENS + (size_t)NB*NTOK;
constexpr size_t OFF_IND  = OFF_SCORE+ (size_t)NB*NTOK;
constexpr size_t OFF_IDXCL= OFF_IND  + (size_t)NB*NS;
constexpr size_t OFF_NORMW= OFF_IDXCL+ (size_t)NB*NTOK;
constexpr size_t OFF_AWBUF= OFF_NORMW+ (size_t)NB*NTOK;
constexpr size_t OFF_XTPK = OFF_AWBUF+ (size_t)NB*NP;
constexpr size_t OFF_XTOKPK= OFF_Y;

__device__ __forceinline__ unsigned pack_hl(float x) {
    unsigned u = __float_as_uint(x);
    unsigned t = u + 0x7fffu + ((u >> 16) & 1u);
    unsigned hibits = t & 0xffff0000u;
    float lo = x - __uint_as_float(hibits);
    unsigned ul = __float_as_uint(lo);
    unsigned lt = ul + 0x7fffu + ((ul >> 16) & 1u);
    return hibits | (lt >> 16);
}
__device__ __forceinline__ unsigned f2bf(float f) {   // RNE bf16 (top 16 bits)
    unsigned u = __float_as_uint(f);
    return (u + 0x7fffu + ((u >> 16) & 1u)) >> 16;
}
__device__ __forceinline__ unsigned hp2(unsigned w0, unsigned w1) {
    return __builtin_amdgcn_perm(w1, w0, 0x07060302u);
}
__device__ __forceinline__ unsigned lp2(unsigned w0, unsigned w1) {
    return __builtin_amdgcn_perm(w1, w0, 0x05040100u);
}

// ---------------- histogram ----------------
__global__ void hist(const float* __restrict__ loc, const int* __restrict__ idxagg,
                     const float* __restrict__ aggw,
                     int* __restrict__ cntmat, float* __restrict__ cnt,
                     float* __restrict__ amat) {
    int bp = blockIdx.x*256 + threadIdx.x;
    int b  = bp >> 14;
    float lx = loc[2*bp+0], ly = loc[2*bp+1];
    lx = fminf(fmaxf(lx, -1.f), 1.f);
    ly = fminf(fmaxf(ly, -1.f), 1.f);
    int px = (int)rintf((lx + 1.f)*32.f - 0.5f); px = min(max(px,0),63);
    int py = (int)rintf((ly + 1.f)*32.f - 0.5f); py = min(max(py,0),63);
    int cell = py*64 + px;
    int tok = idxagg[bp];
    atomicAdd(&cntmat[((size_t)(b*HW64 + cell))*NTOK + tok], 1);
    atomicAdd(&cnt[b*HW64 + cell], 1.0f);
    int qx = (int)rintf((lx + 1.f)*16.f - 0.5f); qx = min(max(qx,0),31);
    int qy = (int)rintf((ly + 1.f)*16.f - 0.5f); qy = min(max(qy,0),31);
    atomicAdd(&amat[((size_t)(b*NTOK + tok))*OHW + qy*32 + qx], aggw[bp]);
}

// x -> xtpk[b][cin][tok] (transposed, packed) AND xpk[b][tok][cin] (straight, packed)
__global__ void xpack_both(const float* __restrict__ x, unsigned* __restrict__ xtpk,
                           unsigned* __restrict__ xpk) {
    int id = blockIdx.x*256 + threadIdx.x;
    int tok = id & 255, cin = (id >> 8) & 255, b = id >> 16;
    unsigned pk = pack_hl(x[((size_t)(b*NTOK + tok))*CIN + cin]);
    xtpk[id] = pk;
    xpk[((size_t)(b*NTOK + tok))*CIN + cin] = pk;
}

// weights in MFMA-fragment order
__global__ void wtrans(const float* __restrict__ convw, uint4* __restrict__ wtf) {
    int tid = blockIdx.x*256 + threadIdx.x;   // 294912
    int lane = tid & 63;
    int r1 = tid >> 6;
    int h = r1 & 1;
    int r2 = r1 >> 1;
    int f = r2 & 3;
    int r3 = r2 >> 2;
    int kc = r3 % NKC, mt = r3 / NKC;
    int cout = mt*64 + f*16 + (lane & 15);
    int kb = kc*32 + (lane >> 4)*8;
    unsigned s[8];
    #pragma unroll
    for (int j = 0; j < 8; ++j) {
        int k = kb + j;
        int grp = k >> 8, cin = k & 255;
        unsigned w = pack_hl(convw[(size_t)cout*KC + cin*9 + grp]);
        s[j] = h ? (w & 0xffffu) : (w >> 16);
    }
    uint4 o;
    o.x = s[0] | (s[1]<<16); o.y = s[2] | (s[3]<<16);
    o.z = s[4] | (s[5]<<16); o.w = s[6] | (s[7]<<16);
    wtf[tid] = o;
}

__global__ void pack4(const float4* __restrict__ src, uint4* __restrict__ dst) {
    size_t i = (size_t)blockIdx.x*256 + threadIdx.x;
    float4 v = src[i];
    uint4 o;
    o.x = pack_hl(v.x); o.y = pack_hl(v.y); o.z = pack_hl(v.z); o.w = pack_hl(v.w);
    dst[i] = o;
}

// ---------------- map_gemm ----------------
__launch_bounds__(512)
__global__ void map_gemm(const int* __restrict__ A, const unsigned* __restrict__ B,
                         const float* __restrict__ cnt, unsigned* __restrict__ xmapu) {
    __shared__ __align__(16) unsigned short Ah[4096];
    __shared__ __align__(16) unsigned short Bh[8192], Bl[8192];
    int z = blockIdx.z, m0 = blockIdx.y*128;
    const int* Ab = A + ((size_t)z*HW64 + m0)*NTOK;
    const unsigned* Bb = B + (size_t)z*CIN*NTOK;
    int t = threadIdx.x, lane = t & 63;
    int w = t >> 6;
    int wm = w >> 2, wn = w & 3;
    int l15 = lane & 15, l4 = lane >> 4;
    int rowA = t & 127, kgA = t >> 7;
    int rowB = t & 255, kgB0 = (t >> 8)*2;
    const int* arow = Ab + (size_t)rowA*NTOK + kgA*8;
    const unsigned* brow = Bb + (size_t)rowB*NTOK + kgB0*8;
    int wbA = (rowA>>4)*512 + kgA*128 + (rowA&15)*8;
    int wbB = (rowB>>4)*512 + kgB0*128 + (rowB&15)*8;

    float4v acc[4][4] = {};
    int4 ia0, ia1;
    uint4 rb[2][2];
    auto loadA = [&](int kc) {
        const int* p = arow + kc*32;
        ia0 = *(const int4*)p; ia1 = *(const int4*)(p + 4);
    };
    auto loadB = [&](int kc) {
        #pragma unroll
        for (int s = 0; s < 2; ++s) {
            const unsigned* p = brow + kc*32 + s*8;
            rb[s][0] = *(const uint4*)p; rb[s][1] = *(const uint4*)(p + 4);
        }
    };
    loadA(0); loadB(0);

    for (int kc = 0; kc < 8; ++kc) {
        __syncthreads();
        uint4 h, l;
        h.x = f2bf((float)ia0.x) | (f2bf((float)ia0.y) << 16);
        h.y = f2bf((float)ia0.z) | (f2bf((float)ia0.w) << 16);
        h.z = f2bf((float)ia1.x) | (f2bf((float)ia1.y) << 16);
        h.w = f2bf((float)ia1.z) | (f2bf((float)ia1.w) << 16);
        *(uint4*)&Ah[wbA] = h;
        #pragma unroll
        for (int s = 0; s < 2; ++s) {
            uint4 u0 = rb[s][0], u1 = rb[s][1];
            h.x=hp2(u0.x,u0.y); h.y=hp2(u0.z,u0.w); h.z=hp2(u1.x,u1.y); h.w=hp2(u1.z,u1.w);
            l.x=lp2(u0.x,u0.y); l.y=lp2(u0.z,u0.w); l.z=lp2(u1.x,u1.y); l.w=lp2(u1.z,u1.w);
            *(uint4*)&Bh[wbB + s*128] = h; *(uint4*)&Bl[wbB + s*128] = l;
        }
        __syncthreads();
        if (kc < 7) { loadA(kc+1); loadB(kc+1); }

        short8v bh[4], bl[4];
        #pragma unroll
        for (int q = 0; q < 4; ++q) {
            int off = (wn*4 + q)*512 + l4*128 + l15*8;
            bh[q] = *(const short8v*)&Bh[off];
            bl[q] = *(const short8v*)&Bl[off];
        }
        #pragma unroll
        for (int p = 0; p < 4; ++p) {
            int off = (wm*4 + p)*512 + l4*128 + l15*8;
            short8v ah = *(const short8v*)&Ah[off];
            #pragma unroll
            for (int q = 0; q < 4; ++q) {
                acc[p][q] = __builtin_amdgcn_mfma_f32_16x16x32_bf16(ah, bh[q], acc[p][q], 0, 0, 0);
                acc[p][q] = __builtin_amdgcn_mfma_f32_16x16x32_bf16(ah, bl[q], acc[p][q], 0, 0, 0);
            }
        }
    }

    const float* cntb = cnt + (size_t)z*HW64;
    #pragma unroll
    for (int p = 0; p < 4; ++p) {
        int mb = m0 + wm*64 + p*16 + l4*4;
        #pragma unroll
        for (int q = 0; q < 4; ++q) {
            int n = wn*64 + q*16 + l15;
            #pragma unroll
            for (int r = 0; r < 4; ++r) {
                float v = acc[p][q][r] / (cntb[mb + r] + EPS);
                xmapu[((size_t)z*HW64 + mb + r)*CIN + n] = pack_hl(v);
            }
        }
    }
}

// ---------------- conv: 128(pos)x64(cout), 2D grid, DEPTH-2 A prefetch ----------------
__launch_bounds__(256)
__global__ void conv_gemm(const unsigned* __restrict__ xmap, const uint4* __restrict__ wtf,
                          const float* __restrict__ convb, unsigned* __restrict__ ytp) {
    __shared__ __align__(16) unsigned short Ahi[2][4096], Alo[2][4096];
    int n0 = blockIdx.x * 128;
    int mt = blockIdx.y;
    int m0 = mt * 64;
    int t = threadIdx.x;
    int lane = t & 63, wid = t >> 6;
    int wm = wid >> 1, wn = wid & 1;
    int l15 = lane & 15, l4 = lane >> 4;

    int rowL = t & 127, kg = t >> 7;
    int posG = n0 + rowL;
    int bb = posG >> 10, rem = posG & 1023;
    int oy = rem >> 5, ox = rem & 31;

    int wbA0 = (rowL>>4)*512 + kg*128 + (rowL&15)*8;
    int wbA1 = wbA0 + 256;

    float4v acc[4][2] = {};
    uint4 aA0,aA1,aA2,aA3;
    uint4 aB0,aB1,aB2,aB3;

    auto addrA = [&](int kc, int* ok) -> const unsigned* {
        int grp = kc >> 3;
        int ky = grp/3, kx = grp - 3*ky;
        int iy = 2*oy - 1 + ky, ix = 2*ox - 1 + kx;
        *ok = ((unsigned)iy < 64u) && ((unsigned)ix < 64u);
        return xmap + ((((size_t)bb*64 + iy)*64 + ix)*256 + (kc&7)*32 + kg*8);
    };
    auto loadA_A = [&](int kc) {
        int ok; const unsigned* ap = addrA(kc, &ok);
        if (ok) {
            aA0 = *(const uint4*)ap;       aA1 = *(const uint4*)(ap + 4);
            aA2 = *(const uint4*)(ap + 16); aA3 = *(const uint4*)(ap + 20);
        } else { aA0 = make_uint4(0,0,0,0); aA1 = aA0; aA2 = aA0; aA3 = aA0; }
    };
    auto loadA_B = [&](int kc) {
        int ok; const unsigned* ap = addrA(kc, &ok);
        if (ok) {
            aB0 = *(const uint4*)ap;       aB1 = *(const uint4*)(ap + 4);
            aB2 = *(const uint4*)(ap + 16); aB3 = *(const uint4*)(ap + 20);
        } else { aB0 = make_uint4(0,0,0,0); aB1 = aB0; aB2 = aB0; aB3 = aB0; }
    };
    auto repack_A = [&](int buf) {
        uint4 h, l;
        h.x=hp2(aA0.x,aA0.y); h.y=hp2(aA0.z,aA0.w); h.z=hp2(aA1.x,aA1.y); h.w=hp2(aA1.z,aA1.w);
        l.x=lp2(aA0.x,aA0.y); l.y=lp2(aA0.z,aA0.w); l.z=lp2(aA1.x,aA1.y); l.w=lp2(aA1.z,aA1.w);
        *(uint4*)&Ahi[buf][wbA0] = h; *(uint4*)&Alo[buf][wbA0] = l;
        h.x=hp2(aA2.x,aA2.y); h.y=hp2(aA2.z,aA2.w); h.z=hp2(aA3.x,aA3.y); h.w=hp2(aA3.z,aA3.w);
        l.x=lp2(aA2.x,aA2.y); l.y=lp2(aA2.z,aA2.w); l.z=lp2(aA3.x,aA3.y); l.w=lp2(aA3.z,aA3.w);
        *(uint4*)&Ahi[buf][wbA1] = h; *(uint4*)&Alo[buf][wbA1] = l;
    };
    auto repack_B = [&](int buf) {
        uint4 h, l;
        h.x=hp2(aB0.x,aB0.y); h.y=hp2(aB0.z,aB0.w); h.z=hp2(aB1.x,aB1.y); h.w=hp2(aB1.z,aB1.w);
        l.x=lp2(aB0.x,aB0.y); l.y=lp2(aB0.z,aB0.w); l.z=lp2(aB1.x,aB1.y); l.w=lp2(aB1.z,aB1.w);
        *(uint4*)&Ahi[buf][wbA0] = h; *(uint4*)&Alo[buf][wbA0] = l;
        h.x=hp2(aB2.x,aB2.y); h.y=hp2(aB2.z,aB2.w); h.z=hp2(aB3.x,aB3.y); h.w=hp2(aB3.z,aB3.w);
        l.x=lp2(aB2.x,aB2.y); l.y=lp2(aB2.z,aB2.w); l.z=lp2(aB3.x,aB3.y); l.w=lp2(aB3.z,aB3.w);
        *(uint4*)&Ahi[buf][wbA1] = h; *(uint4*)&Alo[buf][wbA1] = l;
    };
    const uint4* wbase = wtf + ((size_t)(((mt*NKC)*4 + wn*2)*2))*64 + lane;

    short8v bhc[2], blc[2], bhn[2], bln[2];
    #pragma unroll
    for (int q = 0; q < 2; ++q) {
        bhc[q] = *(const short8v*)(wbase + q*128);
        blc[q] = *(const short8v*)(wbase + q*128 + 64);
    }
    loadA_B(0);
    repack_B(0);
    loadA_A(1);
    __syncthreads();
    int cur = 0;

    #define CONV_MFMA_BLOCK                                                            \
        _Pragma("unroll")                                                              \
        for (int p = 0; p < 4; ++p) {                                                  \
            int off = (wm*4 + p)*512 + l4*128 + l15*8;                                 \
            short8v ah = *(const short8v*)&Ahi[cur][off];                              \
            short8v al = *(const short8v*)&Alo[cur][off];                              \
            _Pragma("unroll")                                                          \
            for (int q = 0; q < 2; ++q) {                                              \
                acc[p][q] = __builtin_amdgcn_mfma_f32_16x16x32_bf16(ah, bhc[q], acc[p][q], 0, 0, 0); \
                acc[p][q] = __builtin_amdgcn_mfma_f32_16x16x32_bf16(ah, blc[q], acc[p][q], 0, 0, 0); \
                acc[p][q] = __builtin_amdgcn_mfma_f32_16x16x32_bf16(al, bhc[q], acc[p][q], 0, 0, 0); \
            }                                                                          \
        }

    for (int kc = 0; kc < NKC; kc += 2) {
        if (kc + 2 < NKC) loadA_B(kc + 2);
        {
            const uint4* wb = wbase + (size_t)(kc+1)*512;
            #pragma unroll
            for (int q = 0; q < 2; ++q) {
                bhn[q] = *(const short8v*)(wb + q*128);
                bln[q] = *(const short8v*)(wb + q*128 + 64);
            }
        }
        CONV_MFMA_BLOCK
        repack_A(cur ^ 1);
        #pragma unroll
        for (int q = 0; q < 2; ++q) { bhc[q] = bhn[q]; blc[q] = bln[q]; }
        __syncthreads();
        cur ^= 1;

        int k1 = kc + 1;
        if (k1 + 2 < NKC) loadA_A(k1 + 2);
        if (k1 + 1 < NKC) {
            const uint4* wb = wbase + (size_t)(k1+1)*512;
            #pragma unroll
            for (int q = 0; q < 2; ++q) {
                bhn[q] = *(const short8v*)(wb + q*128);
                bln[q] = *(const short8v*)(wb + q*128 + 64);
            }
        }
        CONV_MFMA_BLOCK
        if (k1 + 1 < NKC) {
            repack_B(cur ^ 1);
            #pragma unroll
            for (int q = 0; q < 2; ++q) { bhc[q] = bhn[q]; blc[q] = bln[q]; }
        }
        __syncthreads();
        cur ^= 1;
    }
    #undef CONV_MFMA_BLOCK

    int bbk = n0 >> 10;
    int pos0 = (n0 & 1023) + wm*64;
    #pragma unroll
    for (int p = 0; p < 4; ++p) {
        int posb = pos0 + p*16 + l4*4;
        #pragma unroll
        for (int q = 0; q < 2; ++q) {
            int col = m0 + wn*32 + q*16 + l15;
            float bv = convb[col];
            uint4 o;
            o.x = pack_hl(acc[p][q][0] + bv);
            o.y = pack_hl(acc[p][q][1] + bv);
            o.z = pack_hl(acc[p][q][2] + bv);
            o.w = pack_hl(acc[p][q][3] + bv);
            *(uint4*)&ytp[((size_t)(bbk*NCO + col))*OHW + posb] = o;
        }
    }
}

// ---------------- generic split-bf16 MFMA GEMM ----------------
template<int MODE, int TM, int TN, int AF>
__launch_bounds__(256)
__global__ void gemm_pk(const void* __restrict__ Av, const unsigned* __restrict__ B,
                        float* __restrict__ C, int K, int N,
                        long sA, long sB, long sC,
                        const float* __restrict__ aux, unsigned* __restrict__ dmaxU) {
    constexpr int NA = TM/64, NBs = TN/64;
    constexpr int WSM = TM/64;
    constexpr int WSN = 4/WSM;
    constexpr int TWM = TM/WSM, TWN = TN/WSN;
    constexpr int P = TWM/16, Q = TWN/16;
    __shared__ __align__(16) unsigned short Ahi[TM*32], Alo[TM*32];
    __shared__ __align__(16) unsigned short Bhi[TN*32], Blo[TN*32];
    int z = blockIdx.z;
    const unsigned* Ab = (const unsigned*)Av + (size_t)z*sA;
    const unsigned* Bb = B + (size_t)z*sB;
    float* Cb = C + (size_t)z*sC;
    int n0 = blockIdx.x*TN, m0 = blockIdx.y*TM;
    int t = threadIdx.x;
    int lane = t & 63, wid = t >> 6;
    int wm = (WSM==2) ? (wid >> 1) : 0;
    int wn = (WSM==2) ? (wid & 1)  : wid;
    int l15 = lane & 15, l4 = lane >> 4;

    int rowA = t & (TM-1), kgA = t / TM;
    int rowB = t & (TN-1), kgB = t / TN;
    const unsigned* arow = Ab + (size_t)(m0 + rowA)*K + kgA*8;
    const unsigned* brw  = Bb + (size_t)(n0 + rowB)*K + kgB*8;
    int wbA = (rowA>>4)*512 + kgA*128 + (rowA&15)*8;
    int wbB = (rowB>>4)*512 + kgB*128 + (rowB&15)*8;

    float4v acc[P][Q] = {};
    uint4 ra[NA][2], rb[NBs][2];
    auto loadA = [&](int kc) {
        #pragma unroll
        for (int s = 0; s < NA; ++s) {
            const unsigned* p = arow + (size_t)kc*32 + s*16;
            ra[s][0] = *(const uint4*)p; ra[s][1] = *(const uint4*)(p + 4);
        }
    };
    auto loadB = [&](int kc) {
        #pragma unroll
        for (int s = 0; s < NBs; ++s) {
            const unsigned* p = brw + (size_t)kc*32 + s*16;
            rb[s][0] = *(const uint4*)p; rb[s][1] = *(const uint4*)(p + 4);
        }
    };
    loadA(0); loadB(0);
    int nkc = K >> 5;

    for (int kc = 0; kc < nkc; ++kc) {
        __syncthreads();
        uint4 h, l;
        #pragma unroll
        for (int s = 0; s < NA; ++s) {
            uint4 u0 = ra[s][0], u1 = ra[s][1];
            if (AF == 0) {
                h.x=hp2(u0.x,u0.y); h.y=hp2(u0.z,u0.w); h.z=hp2(u1.x,u1.y); h.w=hp2(u1.z,u1.w);
                l.x=lp2(u0.x,u0.y); l.y=lp2(u0.z,u0.w); l.z=lp2(u1.x,u1.y); l.w=lp2(u1.z,u1.w);
            } else {
                unsigned pk0 = pack_hl(__uint_as_float(u0.x)), pk1 = pack_hl(__uint_as_float(u0.y));
                unsigned pk2 = pack_hl(__uint_as_float(u0.z)), pk3 = pack_hl(__uint_as_float(u0.w));
                unsigned pk4 = pack_hl(__uint_as_float(u1.x)), pk5 = pack_hl(__uint_as_float(u1.y));
                unsigned pk6 = pack_hl(__uint_as_float(u1.z)), pk7 = pack_hl(__uint_as_float(u1.w));
                h.x = (pk0>>16) | (pk1 & 0xffff0000u); h.y = (pk2>>16) | (pk3 & 0xffff0000u);
                h.z = (pk4>>16) | (pk5 & 0xffff0000u); h.w = (pk6>>16) | (pk7 & 0xffff0000u);
                l.x = (pk0&0xffffu) | (pk1<<16); l.y = (pk2&0xffffu) | (pk3<<16);
                l.z = (pk4&0xffffu) | (pk5<<16); l.w = (pk6&0xffffu) | (pk7<<16);
            }
            *(uint4*)&Ahi[wbA + s*256] = h; *(uint4*)&Alo[wbA + s*256] = l;
        }
        #pragma unroll
        for (int s = 0; s < NBs; ++s) {
            uint4 u0 = rb[s][0], u1 = rb[s][1];
            h.x=hp2(u0.x,u0.y); h.y=hp2(u0.z,u0.w); h.z=hp2(u1.x,u1.y); h.w=hp2(u1.z,u1.w);
            l.x=lp2(u0.x,u0.y); l.y=lp2(u0.z,u0.w); l.z=lp2(u1.x,u1.y); l.w=lp2(u1.z,u1.w);
            *(uint4*)&Bhi[wbB + s*256] = h; *(uint4*)&Blo[wbB + s*256] = l;
        }
        __syncthreads();
        if (kc + 1 < nkc) { loadA(kc+1); loadB(kc+1); }

        short8v bh[Q], bl[Q];
        #pragma unroll
        for (int q = 0; q < Q; ++q) {
            int off = (wn*Q + q)*512 + l4*128 + l15*8;
            bh[q] = *(const short8v*)&Bhi[off];
            bl[q] = *(const short8v*)&Blo[off];
        }
        #pragma unroll
        for (int p = 0; p < P; ++p) {
            int off = (wm*P + p)*512 + l4*128 + l15*8;
            short8v ah = *(const short8v*)&Ahi[off];
            short8v al = *(const short8v*)&Alo[off];
            #pragma unroll
            for (int q = 0; q < Q; ++q) {
                acc[p][q] = __builtin_amdgcn_mfma_f32_16x16x32_bf16(ah, bh[q], acc[p][q], 0, 0, 0);
                acc[p][q] = __builtin_amdgcn_mfma_f32_16x16x32_bf16(ah, bl[q], acc[p][q], 0, 0, 0);
                acc[p][q] = __builtin_amdgcn_mfma_f32_16x16x32_bf16(al, bh[q], acc[p][q], 0, 0, 0);
            }
        }
    }

    if (MODE == 0) {
        #pragma unroll
        for (int p = 0; p < P; ++p) {
            int mb = m0 + wm*TWM + p*16 + l4*4;
            #pragma unroll
            for (int q = 0; q < Q; ++q) {
                int n = n0 + wn*TWN + q*16 + l15;
                #pragma unroll
                for (int r = 0; r < 4; ++r)
                    Cb[(size_t)(mb + r)*N + n] = acc[p][q][r];
            }
        }
    } else {
        const float inv = 1.0f / sqrtf(512.0f);
        const float* sqb = aux + (size_t)z*NTOK;
        float tmax = 0.f;
        #pragma unroll
        for (int p = 0; p < P; ++p) {
            int mb = m0 + wm*TWM + p*16 + l4*4;
            #pragma unroll
            for (int q = 0; q < Q; ++q) {
                int n = n0 + wn*TWN + q*16 + l15;
                float sn = sqb[n];
                #pragma unroll
                for (int r = 0; r < 4; ++r) {
                    float d2 = sqb[mb + r] + sn - 2.0f*acc[p][q][r];
                    float d = sqrtf(fmaxf(d2, 0.0f)) * inv;
                    Cb[(size_t)(mb + r)*N + n] = d;
                    tmax = fmaxf(tmax, d);
                }
            }
        }
        __shared__ float redm[4];
        #pragma unroll
        for (int off = 32; off; off >>= 1) tmax = fmaxf(tmax, __shfl_xor(tmax, off, 64));
        if (lane == 0) redm[wid] = tmax;
        __syncthreads();
        if (t == 0) {
            float m = fmaxf(fmaxf(redm[0], redm[1]), fmaxf(redm[2], redm[3]));
            atomicMax(dmaxU + z, __float_as_uint(m));
        }
    }
}

// ---------------- remaining pipeline ----------------
__global__ void wsum_rows(const float* __restrict__ amat, float* __restrict__ wsum) {
    int row = blockIdx.x*4 + (threadIdx.x >> 6);
    int lane = threadIdx.x & 63;
    const float* ar = amat + (size_t)row*OHW;
    float s = 0.f;
    #pragma unroll
    for (int r = 0; r < 16; ++r) s += ar[lane + 64*r];
    #pragma unroll
    for (int off = 32; off; off >>= 1) s += __shfl_xor(s, off, 64);
    if (lane == 0) wsum[row] = s;
}

__device__ __forceinline__ float block_sum256(float v, float* red) {
    #pragma unroll
    for (int off = 32; off; off >>= 1) v += __shfl_xor(v, off, 64);
    __syncthreads();
    if ((threadIdx.x & 63) == 0) red[threadIdx.x >> 6] = v;
    __syncthreads();
    return red[0] + red[1] + red[2] + red[3];
}

__global__ void ln_conf(const float* __restrict__ C2, const float* __restrict__ wsum,
                        const float* __restrict__ xskip, const float* __restrict__ g,
                        const float* __restrict__ be, const float* __restrict__ confw,
                        const float* __restrict__ confb, float* __restrict__ xtok,
                        unsigned* __restrict__ xtokpk,
                        float* __restrict__ wexp, float* __restrict__ sqv) {
    __shared__ float red[4];
    int row = blockIdx.x, t = threadIdx.x;
    float ws = wsum[row] + EPS;
    size_t base = (size_t)row*NCO;
    float v0 = C2[base + t]       / ws + xskip[base + t];
    float v1 = C2[base + t + 256] / ws + xskip[base + t + 256];
    float mu  = block_sum256(v0 + v1, red) / 512.0f;
    float d0 = v0 - mu, d1 = v1 - mu;
    float var = block_sum256(d0*d0 + d1*d1, red) / 512.0f;
    float sv = sqrtf(var + 1e-5f);
    float x0 = d0/sv * g[t]       + be[t];
    float x1 = d1/sv * g[t + 256] + be[t + 256];
    xtok[base + t] = x0;
    xtok[base + t + 256] = x1;
    xtokpk[base + t] = pack_hl(x0);
    xtokpk[base + t + 256] = pack_hl(x1);
    float cs = block_sum256(x0*confw[t] + x1*confw[t + 256], red);
    float qs = block_sum256(x0*x0 + x1*x1, red);
    if (t == 0) {
        wexp[row] = expf(cs + confb[0]);
        sqv[row]  = qs;
    }
}

__global__ void knn_dens(const float* __restrict__ dist, float* __restrict__ dens) {
    int row = blockIdx.x*4 + (threadIdx.x >> 6);
    int lane = threadIdx.x & 63;
    const float* dr = dist + (size_t)row*NTOK;
    float v0 = dr[lane], v1 = dr[lane+64], v2 = dr[lane+128], v3 = dr[lane+192];
    float acc = 0.f;
    #pragma unroll
    for (int it = 0; it < 5; ++it) {
        float lm = fminf(fminf(v0, v1), fminf(v2, v3));
        float gm = lm;
        #pragma unroll
        for (int off = 32; off; off >>= 1) gm = fminf(gm, __shfl_xor(gm, off, 64));
        acc += gm*gm;
        ull ball = __ballot(lm == gm);
        int first = __ffsll(ball) - 1;
        if (lane == first) {
            if      (v0 == gm) v0 = 1e30f;
            else if (v1 == gm) v1 = 1e30f;
            else if (v2 == gm) v2 = 1e30f;
            else               v3 = 1e30f;
        }
    }
    if (lane == 0) dens[row] = expf(-(acc/5.0f));
}

__global__ void parent_score(const float* __restrict__ dist, const float* __restrict__ dens,
                             const unsigned* __restrict__ dmaxU, float* __restrict__ score) {
    int row = blockIdx.x*4 + (threadIdx.x >> 6);
    int lane = threadIdx.x & 63;
    int b = row >> 8;
    float di = dens[row];
    float dm = __uint_as_float(dmaxU[b]);
    const float* dr = dist + (size_t)row*NTOK;
    const float* db = dens + (size_t)b*NTOK;
    float pd = dm;
    #pragma unroll
    for (int r = 0; r < 4; ++r) {
        int j = lane + 64*r;
        pd = fminf(pd, (db[j] > di) ? dr[j] : dm);
    }
    #pragma unroll
    for (int off = 32; off; off >>= 1) pd = fminf(pd, __shfl_xor(pd, off, 64));
    if (lane == 0) score[row] = pd * di;
}

__global__ void topk64(const float* __restrict__ score, int* __restrict__ ind) {
    int b = blockIdx.x, lane = threadIdx.x;
    const float* sb = score + b*NTOK;
    ull k0, k1, k2, k3;
    {
        unsigned i0 = lane, i1 = lane+64, i2 = lane+128, i3 = lane+192;
        k0 = ((ull)(__float_as_uint(sb[i0]) + 1u) << 32) | (unsigned)(4095 - i0);
        k1 = ((ull)(__float_as_uint(sb[i1]) + 1u) << 32) | (unsigned)(4095 - i1);
        k2 = ((ull)(__float_as_uint(sb[i2]) + 1u) << 32) | (unsigned)(4095 - i2);
        k3 = ((ull)(__float_as_uint(sb[i3]) + 1u) << 32) | (unsigned)(4095 - i3);
    }
    for (int it = 0; it < 64; ++it) {
        ull lm = k0;
        if (k1 > lm) lm = k1;
        if (k2 > lm) lm = k2;
        if (k3 > lm) lm = k3;
        ull gm = lm;
        #pragma unroll
        for (int off = 32; off; off >>= 1) {
            ull o = __shfl_xor(gm, off, 64);
            if (o > gm) gm = o;
        }
        if (lane == 0) ind[b*NS + it] = 4095 - (int)(gm & 0xffffffffull);
        if      (k0 == gm) k0 = 0;
        else if (k1 == gm) k1 = 0;
        else if (k2 == gm) k2 = 0;
        else if (k3 == gm) k3 = 0;
    }
}

__global__ void assign_k(const float* __restrict__ dist, const int* __restrict__ ind,
                         int* __restrict__ idxcl) {
    int row = blockIdx.x*4 + (threadIdx.x >> 6);
    int lane = threadIdx.x & 63;
    int b = row >> 8, i = row & 255;
    int center = ind[b*NS + lane];
    float d = dist[((size_t)(b*NTOK + center))*NTOK + i];
    ull key = ((ull)__float_as_uint(d) << 32) | (unsigned)lane;
    #pragma unroll
    for (int off = 32; off; off >>= 1) {
        ull o = __shfl_xor(key, off, 64);
        if (o < key) key = o;
    }
    if (lane == 0) idxcl[row] = (int)(key & 0xffffffffull);
}

// fused: center self-assign + allw accumulation (LDS) + normw. grid(NB), 256 thr.
__global__ void finalize_cl(const int* __restrict__ ind, const float* __restrict__ wexp,
                            int* __restrict__ idxcl, float* __restrict__ normw) {
    __shared__ float allwL[NS];
    int b = blockIdx.x, t = threadIdx.x;
    if (t < NS) {
        idxcl[b*NTOK + ind[b*NS + t]] = t;
        allwL[t] = 0.f;
    }
    __syncthreads();
    int cl = idxcl[b*NTOK + t];
    float we = wexp[b*NTOK + t];
    atomicAdd(&allwL[cl], we);
    __syncthreads();
    normw[b*NTOK + t] = we / (allwL[cl] + EPS);
}

__global__ void merge_k(const float* __restrict__ xtok, const int* __restrict__ idxcl,
                        const float* __restrict__ normw, float* __restrict__ xout) {
    int row = blockIdx.x, t = threadIdx.x;
    int b = row >> 8;
    int cl = idxcl[row];
    float nw = normw[row];
    float* o = xout + ((size_t)(b*NS + cl))*NCO;
    const float* xr = xtok + (size_t)row*NCO;
    atomicAdd(&o[t],       xr[t]       * nw);
    atomicAdd(&o[t + 256], xr[t + 256] * nw);
}

__global__ void out_idx_aw(const int* __restrict__ idxagg, const float* __restrict__ aggw,
                           const int* __restrict__ idxcl, const float* __restrict__ normw,
                           float* __restrict__ dout, float* __restrict__ awbuf,
                           unsigned* __restrict__ maxw) {
    __shared__ float red[4];
    int bp = blockIdx.x*256 + threadIdx.x;
    int b = bp >> 14;
    int tok = idxagg[bp];
    int cl = idxcl[b*NTOK + tok];
    dout[(size_t)NB*NS*NCO + bp] = (float)cl;
    float aw = aggw[bp] * normw[b*NTOK + tok];
    awbuf[bp] = aw;
    float m = aw;
    #pragma unroll
    for (int off = 32; off; off >>= 1) m = fmaxf(m, __shfl_xor(m, off, 64));
    if ((threadIdx.x & 63) == 0) red[threadIdx.x >> 6] = m;
    __syncthreads();
    if (threadIdx.x == 0) {
        float mm = fmaxf(fmaxf(red[0], red[1]), fmaxf(red[2], red[3]));
        atomicMax(&maxw[b], __float_as_uint(mm));
    }
}

__global__ void aw_final(const float* __restrict__ awbuf, const float* __restrict__ maxw,
                         float* __restrict__ dout) {
    int bp = blockIdx.x*256 + threadIdx.x;
    int b = bp >> 14;
    dout[(size_t)NB*NS*NCO + (size_t)NB*NP + bp] = awbuf[bp] / maxw[b];
}

// ---------------- launch ----------------
extern "C" void kernel_launch(void* const* d_in, const int* in_sizes, int n_in,
                              void* d_out, int out_size, void* d_ws, size_t ws_size,
                              hipStream_t stream) {
    const float* x      = (const float*)d_in[0];
    const float* loc    = (const float*)d_in[1];
    const int*   idxagg = (const int*)  d_in[2];
    const float* aggw   = (const float*)d_in[3];
    const float* convw  = (const float*)d_in[7];
    const float* convb  = (const float*)d_in[8];
    const float* skipw  = (const float*)d_in[9];
    const float* lng    = (const float*)d_in[10];
    const float* lnb    = (const float*)d_in[11];
    const float* confw  = (const float*)d_in[12];
    const float* confb  = (const float*)d_in[13];

    float* ws = (float*)d_ws;
    float* dout = (float*)d_out;

    (void)hipMemsetAsync(ws, 0, ZERO_END*sizeof(float), stream);
    (void)hipMemsetAsync(dout, 0, (size_t)NB*NS*NCO*sizeof(float), stream);

    hist<<<dim3(NB*NP/256), 256, 0, stream>>>(loc, idxagg, aggw,
                                              (int*)(ws + OFF_SUMS), ws + OFF_CNT, ws + OFF_AMAT);
    xpack_both<<<dim3(NB*CIN*NTOK/256), 256, 0, stream>>>(x, (unsigned*)(ws + OFF_XTPK),
                                                          (unsigned*)(ws + OFF_XPK));
    wtrans<<<dim3(1152), 256, 0, stream>>>(convw, (uint4*)(ws + OFF_WT));
    pack4<<<dim3(CIN*NCO/1024), 256, 0, stream>>>((const float4*)skipw, (uint4*)(ws + OFF_SKWT));

    map_gemm<<<dim3(1, 32, 8), 512, 0, stream>>>((const int*)(ws + OFF_SUMS),
                                                 (const unsigned*)(ws + OFF_XTPK),
                                                 ws + OFF_CNT,
                                                 (unsigned*)(ws + OFF_SUMS));

    conv_gemm<<<dim3(64, 8), 256, 0, stream>>>((const unsigned*)(ws + OFF_SUMS),
                                               (const uint4*)(ws + OFF_WT), convb,
                                               (unsigned*)(ws + OFF_Y));

    wsum_rows<<<dim3(NB*NTOK/4), 256, 0, stream>>>(ws + OFF_AMAT, ws + OFF_WSUM);
    gemm_pk<0,64,64,1><<<dim3(8, 4, 8), 256, 0, stream>>>((const void*)(ws + OFF_AMAT),
                                                  (const unsigned*)(ws + OFF_Y),
                                                  ws + OFF_C2, OHW, NCO,
                                                  (long)NTOK*OHW, (long)NCO*OHW, (long)NTOK*NCO,
                                                  nullptr, nullptr);
    gemm_pk<0,64,64,0><<<dim3(8, 32, 1), 256, 0, stream>>>((const void*)(ws + OFF_XPK),
                                                   (const unsigned*)(ws + OFF_SKWT),
                                                   ws + OFF_XSKIP, CIN, NCO, 0, 0, 0,
                                                   nullptr, nullptr);

    ln_conf<<<dim3(NB*NTOK), 256, 0, stream>>>(ws + OFF_C2, ws + OFF_WSUM, ws + OFF_XSKIP,
                                               lng, lnb, confw, confb,
                                               ws + OFF_XTOK, (unsigned*)(ws + OFF_XTOKPK),
                                               ws + OFF_WEXP, ws + OFF_SQ);

    gemm_pk<1,64,64,0><<<dim3(4, 4, 8), 256, 0, stream>>>((const void*)(ws + OFF_XTOKPK),
                                                  (const unsigned*)(ws + OFF_XTOKPK),
                                                  ws + OFF_DIST, NCO, NTOK,
                                                  (long)NTOK*NCO, (long)NTOK*NCO, (long)NTOK*NTOK,
                                                  ws + OFF_SQ, (unsigned*)(ws + OFF_DMAX));

    knn_dens<<<dim3(NB*NTOK/4), 256, 0, stream>>>(ws + OFF_DIST, ws + OFF_DENS);
    parent_score<<<dim3(NB*NTOK/4), 256, 0, stream>>>(ws + OFF_DIST, ws + OFF_DENS,
                                                      (const unsigned*)(ws + OFF_DMAX), ws + OFF_SCORE);
    topk64<<<dim3(NB), 64, 0, stream>>>(ws + OFF_SCORE, (int*)(ws + OFF_IND));
    assign_k<<<dim3(NB*NTOK/4), 256, 0, stream>>>(ws + OFF_DIST, (const int*)(ws + OFF_IND),
                                                  (int*)(ws + OFF_IDXCL));
    finalize_cl<<<dim3(NB), 256, 0, stream>>>((const int*)(ws + OFF_IND), ws + OFF_WEXP,
                                              (int*)(ws + OFF_IDXCL), ws + OFF_NORMW);

    merge_k<<<dim3(NB*NTOK), 256, 0, stream>>>(ws + OFF_XTOK, (const int*)(ws + OFF_IDXCL),
                                               ws + OFF_NORMW, dout);
    out_idx_aw<<<dim3(NB*NP/256), 256, 0, stream>>>(idxagg, aggw, (const int*)(ws + OFF_IDXCL),
                                                    ws + OFF_NORMW, dout, ws + OFF_AWBUF,
                                                    (unsigned*)(ws + OFF_MAXW));
    aw_final<<<dim3(NB*NP/256), 256, 0, stream>>>(ws + OFF_AWBUF, (const float*)(ws + OFF_MAXW), dout);
}

// Round 13
// 282.083 us; speedup vs baseline: 1.5771x; 1.0491x over previous
//
#include <hip/hip_runtime.h>
#include <math.h>

typedef unsigned long long ull;
typedef __attribute__((ext_vector_type(8))) short short8v;   // 8 bf16 in 4 VGPRs
typedef __attribute__((ext_vector_type(4))) float float4v;

#define NB   8
#define NTOK 256
#define CIN  256
#define NP   16384
#define NCO  512
#define HW64 4096
#define OHW  1024
#define NS   64
#define EPS  1e-6f
#define KC   2304   // 9*256 conv K
#define NKC  72     // KC/32

// ---------------- workspace layout (float offsets) ----------------
constexpr size_t OFF_SUMS = 0;                                   // cntmat(int) -> xmap packed (in-place map_gemm)
constexpr size_t OFF_CNT  = OFF_SUMS + (size_t)NB*HW64*CIN;
constexpr size_t OFF_AMAT = OFF_CNT  + (size_t)NB*HW64;          // f32, consumed directly by ssum (AF=1)
constexpr size_t OFF_ALLW = OFF_AMAT + (size_t)NB*NTOK*OHW;
constexpr size_t OFF_DMAX = OFF_ALLW + (size_t)NB*NS;
constexpr size_t OFF_MAXW = OFF_DMAX + NB;
constexpr size_t ZERO_END = OFF_MAXW + NB;
constexpr size_t OFF_WT   = ZERO_END;                            // frag-major weights
constexpr size_t OFF_SKWT = OFF_WT   + (size_t)KC*NCO;
constexpr size_t OFF_Y    = OFF_SKWT + (size_t)CIN*NCO;          // yT packed (conv); after ssum: XTOKPK alias
constexpr size_t OFF_C2   = OFF_Y    + (size_t)NB*OHW*NCO;
constexpr size_t OFF_WSUM = OFF_C2   + (size_t)NB*NTOK*NCO;
constexpr size_t OFF_XSKIP= OFF_WSUM + (size_t)NB*NTOK;
constexpr size_t OFF_XTOK = OFF_XSKIP+ (size_t)NB*NTOK*NCO;
constexpr size_t OFF_XPK  = OFF_XTOK + (size_t)NB*NTOK*NCO;
constexpr size_t OFF_WEXP = OFF_XPK  + (size_t)NB*NTOK*NCO;
constexpr size_t OFF_SQ   = OFF_WEXP + (size_t)NB*NTOK;
constexpr size_t OFF_DIST = OFF_SQ   + (size_t)NB*NTOK;
constexpr size_t OFF_DENS = OFF_DIST + (size_t)NB*NTOK*NTOK;
constexpr size_t OFF_SCORE= OFF_DENS + (size_t)NB*NTOK;
constexpr size_t OFF_IND  = OFF_SCORE+ (size_t)NB*NTOK;
constexpr size_t OFF_IDXCL= OFF_IND  + (size_t)NB*NS;
constexpr size_t OFF_NORMW= OFF_IDXCL+ (size_t)NB*NTOK;
constexpr size_t OFF_AWBUF= OFF_NORMW+ (size_t)NB*NTOK;
constexpr size_t OFF_XTPK = OFF_AWBUF+ (size_t)NB*NP;
constexpr size_t OFF_XTOKPK= OFF_Y;

__device__ __forceinline__ unsigned pack_hl(float x) {
    unsigned u = __float_as_uint(x);
    unsigned t = u + 0x7fffu + ((u >> 16) & 1u);
    unsigned hibits = t & 0xffff0000u;
    float lo = x - __uint_as_float(hibits);
    unsigned ul = __float_as_uint(lo);
    unsigned lt = ul + 0x7fffu + ((ul >> 16) & 1u);
    return hibits | (lt >> 16);
}
__device__ __forceinline__ unsigned f2bf(float f) {   // RNE bf16 (top 16 bits)
    unsigned u = __float_as_uint(f);
    return (u + 0x7fffu + ((u >> 16) & 1u)) >> 16;
}
__device__ __forceinline__ unsigned hp2(unsigned w0, unsigned w1) {
    return __builtin_amdgcn_perm(w1, w0, 0x07060302u);
}
__device__ __forceinline__ unsigned lp2(unsigned w0, unsigned w1) {
    return __builtin_amdgcn_perm(w1, w0, 0x05040100u);
}

// ---------------- histogram ----------------
__global__ void hist(const float* __restrict__ loc, const int* __restrict__ idxagg,
                     const float* __restrict__ aggw,
                     int* __restrict__ cntmat, float* __restrict__ cnt,
                     float* __restrict__ amat) {
    int bp = blockIdx.x*256 + threadIdx.x;
    int b  = bp >> 14;
    float lx = loc[2*bp+0], ly = loc[2*bp+1];
    lx = fminf(fmaxf(lx, -1.f), 1.f);
    ly = fminf(fmaxf(ly, -1.f), 1.f);
    int px = (int)rintf((lx + 1.f)*32.f - 0.5f); px = min(max(px,0),63);
    int py = (int)rintf((ly + 1.f)*32.f - 0.5f); py = min(max(py,0),63);
    int cell = py*64 + px;
    int tok = idxagg[bp];
    atomicAdd(&cntmat[((size_t)(b*HW64 + cell))*NTOK + tok], 1);
    atomicAdd(&cnt[b*HW64 + cell], 1.0f);
    int qx = (int)rintf((lx + 1.f)*16.f - 0.5f); qx = min(max(qx,0),31);
    int qy = (int)rintf((ly + 1.f)*16.f - 0.5f); qy = min(max(qy,0),31);
    atomicAdd(&amat[((size_t)(b*NTOK + tok))*OHW + qy*32 + qx], aggw[bp]);
}

// fused prep: xpack_both (blocks 0..2047) | wtrans (2048..3199) | pack4 skipw (3200..3327)
__global__ void prep_pack(const float* __restrict__ x, unsigned* __restrict__ xtpk,
                          unsigned* __restrict__ xpk,
                          const float* __restrict__ convw, uint4* __restrict__ wtf,
                          const float4* __restrict__ skipw, uint4* __restrict__ skwt) {
    int blk = blockIdx.x;
    if (blk < 2048) {
        int id = blk*256 + threadIdx.x;
        int tok = id & 255, cin = (id >> 8) & 255, b = id >> 16;
        unsigned pk = pack_hl(x[((size_t)(b*NTOK + tok))*CIN + cin]);
        xtpk[id] = pk;
        xpk[((size_t)(b*NTOK + tok))*CIN + cin] = pk;
    } else if (blk < 3200) {
        int tid = (blk - 2048)*256 + threadIdx.x;   // 294912
        int lane = tid & 63;
        int r1 = tid >> 6;
        int h = r1 & 1;
        int r2 = r1 >> 1;
        int f = r2 & 3;
        int r3 = r2 >> 2;
        int kc = r3 % NKC, mt = r3 / NKC;
        int cout = mt*64 + f*16 + (lane & 15);
        int kb = kc*32 + (lane >> 4)*8;
        unsigned s[8];
        #pragma unroll
        for (int j = 0; j < 8; ++j) {
            int k = kb + j;
            int grp = k >> 8, cin = k & 255;
            unsigned w = pack_hl(convw[(size_t)cout*KC + cin*9 + grp]);
            s[j] = h ? (w & 0xffffu) : (w >> 16);
        }
        uint4 o;
        o.x = s[0] | (s[1]<<16); o.y = s[2] | (s[3]<<16);
        o.z = s[4] | (s[5]<<16); o.w = s[6] | (s[7]<<16);
        wtf[tid] = o;
    } else {
        size_t i = (size_t)(blk - 3200)*256 + threadIdx.x;   // 32768 uint4
        float4 v = skipw[i];
        uint4 o;
        o.x = pack_hl(v.x); o.y = pack_hl(v.y); o.z = pack_hl(v.z); o.w = pack_hl(v.w);
        skwt[i] = o;
    }
}

// ---------------- map_gemm ----------------
__launch_bounds__(512)
__global__ void map_gemm(const int* __restrict__ A, const unsigned* __restrict__ B,
                         const float* __restrict__ cnt, unsigned* __restrict__ xmapu) {
    __shared__ __align__(16) unsigned short Ah[4096];
    __shared__ __align__(16) unsigned short Bh[8192], Bl[8192];
    int z = blockIdx.z, m0 = blockIdx.y*128;
    const int* Ab = A + ((size_t)z*HW64 + m0)*NTOK;
    const unsigned* Bb = B + (size_t)z*CIN*NTOK;
    int t = threadIdx.x, lane = t & 63;
    int w = t >> 6;
    int wm = w >> 2, wn = w & 3;
    int l15 = lane & 15, l4 = lane >> 4;
    int rowA = t & 127, kgA = t >> 7;
    int rowB = t & 255, kgB0 = (t >> 8)*2;
    const int* arow = Ab + (size_t)rowA*NTOK + kgA*8;
    const unsigned* brow = Bb + (size_t)rowB*NTOK + kgB0*8;
    int wbA = (rowA>>4)*512 + kgA*128 + (rowA&15)*8;
    int wbB = (rowB>>4)*512 + kgB0*128 + (rowB&15)*8;

    float4v acc[4][4] = {};
    int4 ia0, ia1;
    uint4 rb[2][2];
    auto loadA = [&](int kc) {
        const int* p = arow + kc*32;
        ia0 = *(const int4*)p; ia1 = *(const int4*)(p + 4);
    };
    auto loadB = [&](int kc) {
        #pragma unroll
        for (int s = 0; s < 2; ++s) {
            const unsigned* p = brow + kc*32 + s*8;
            rb[s][0] = *(const uint4*)p; rb[s][1] = *(const uint4*)(p + 4);
        }
    };
    loadA(0); loadB(0);

    for (int kc = 0; kc < 8; ++kc) {
        __syncthreads();
        uint4 h, l;
        h.x = f2bf((float)ia0.x) | (f2bf((float)ia0.y) << 16);
        h.y = f2bf((float)ia0.z) | (f2bf((float)ia0.w) << 16);
        h.z = f2bf((float)ia1.x) | (f2bf((float)ia1.y) << 16);
        h.w = f2bf((float)ia1.z) | (f2bf((float)ia1.w) << 16);
        *(uint4*)&Ah[wbA] = h;
        #pragma unroll
        for (int s = 0; s < 2; ++s) {
            uint4 u0 = rb[s][0], u1 = rb[s][1];
            h.x=hp2(u0.x,u0.y); h.y=hp2(u0.z,u0.w); h.z=hp2(u1.x,u1.y); h.w=hp2(u1.z,u1.w);
            l.x=lp2(u0.x,u0.y); l.y=lp2(u0.z,u0.w); l.z=lp2(u1.x,u1.y); l.w=lp2(u1.z,u1.w);
            *(uint4*)&Bh[wbB + s*128] = h; *(uint4*)&Bl[wbB + s*128] = l;
        }
        __syncthreads();
        if (kc < 7) { loadA(kc+1); loadB(kc+1); }

        short8v bh[4], bl[4];
        #pragma unroll
        for (int q = 0; q < 4; ++q) {
            int off = (wn*4 + q)*512 + l4*128 + l15*8;
            bh[q] = *(const short8v*)&Bh[off];
            bl[q] = *(const short8v*)&Bl[off];
        }
        #pragma unroll
        for (int p = 0; p < 4; ++p) {
            int off = (wm*4 + p)*512 + l4*128 + l15*8;
            short8v ah = *(const short8v*)&Ah[off];
            #pragma unroll
            for (int q = 0; q < 4; ++q) {
                acc[p][q] = __builtin_amdgcn_mfma_f32_16x16x32_bf16(ah, bh[q], acc[p][q], 0, 0, 0);
                acc[p][q] = __builtin_amdgcn_mfma_f32_16x16x32_bf16(ah, bl[q], acc[p][q], 0, 0, 0);
            }
        }
    }

    const float* cntb = cnt + (size_t)z*HW64;
    #pragma unroll
    for (int p = 0; p < 4; ++p) {
        int mb = m0 + wm*64 + p*16 + l4*4;
        #pragma unroll
        for (int q = 0; q < 4; ++q) {
            int n = wn*64 + q*16 + l15;
            #pragma unroll
            for (int r = 0; r < 4; ++r) {
                float v = acc[p][q][r] / (cntb[mb + r] + EPS);
                xmapu[((size_t)z*HW64 + mb + r)*CIN + n] = pack_hl(v);
            }
        }
    }
}

// ---------------- conv: 128(pos)x64(cout), 2D grid, depth-2 A prefetch, vmcnt-ORDERED ----------------
// KEY FIX vs R12: B-frag loads issued BEFORE the A kc+2 prefetch, so the bhc=bhn copy's
// implicit vmcnt wait (FIFO retire) does NOT drain the A prefetch.
__launch_bounds__(256)
__global__ void conv_gemm(const unsigned* __restrict__ xmap, const uint4* __restrict__ wtf,
                          const float* __restrict__ convb, unsigned* __restrict__ ytp) {
    __shared__ __align__(16) unsigned short Ahi[2][4096], Alo[2][4096];
    int n0 = blockIdx.x * 128;
    int mt = blockIdx.y;
    int m0 = mt * 64;
    int t = threadIdx.x;
    int lane = t & 63, wid = t >> 6;
    int wm = wid >> 1, wn = wid & 1;
    int l15 = lane & 15, l4 = lane >> 4;

    int rowL = t & 127, kg = t >> 7;
    int posG = n0 + rowL;
    int bb = posG >> 10, rem = posG & 1023;
    int oy = rem >> 5, ox = rem & 31;

    int wbA0 = (rowL>>4)*512 + kg*128 + (rowL&15)*8;
    int wbA1 = wbA0 + 256;

    float4v acc[4][2] = {};
    uint4 aA0,aA1,aA2,aA3;
    uint4 aB0,aB1,aB2,aB3;

    auto addrA = [&](int kc, int* ok) -> const unsigned* {
        int grp = kc >> 3;
        int ky = grp/3, kx = grp - 3*ky;
        int iy = 2*oy - 1 + ky, ix = 2*ox - 1 + kx;
        *ok = ((unsigned)iy < 64u) && ((unsigned)ix < 64u);
        return xmap + ((((size_t)bb*64 + iy)*64 + ix)*256 + (kc&7)*32 + kg*8);
    };
    auto loadA_A = [&](int kc) {
        int ok; const unsigned* ap = addrA(kc, &ok);
        if (ok) {
            aA0 = *(const uint4*)ap;       aA1 = *(const uint4*)(ap + 4);
            aA2 = *(const uint4*)(ap + 16); aA3 = *(const uint4*)(ap + 20);
        } else { aA0 = make_uint4(0,0,0,0); aA1 = aA0; aA2 = aA0; aA3 = aA0; }
    };
    auto loadA_B = [&](int kc) {
        int ok; const unsigned* ap = addrA(kc, &ok);
        if (ok) {
            aB0 = *(const uint4*)ap;       aB1 = *(const uint4*)(ap + 4);
            aB2 = *(const uint4*)(ap + 16); aB3 = *(const uint4*)(ap + 20);
        } else { aB0 = make_uint4(0,0,0,0); aB1 = aB0; aB2 = aB0; aB3 = aB0; }
    };
    auto repack_A = [&](int buf) {
        uint4 h, l;
        h.x=hp2(aA0.x,aA0.y); h.y=hp2(aA0.z,aA0.w); h.z=hp2(aA1.x,aA1.y); h.w=hp2(aA1.z,aA1.w);
        l.x=lp2(aA0.x,aA0.y); l.y=lp2(aA0.z,aA0.w); l.z=lp2(aA1.x,aA1.y); l.w=lp2(aA1.z,aA1.w);
        *(uint4*)&Ahi[buf][wbA0] = h; *(uint4*)&Alo[buf][wbA0] = l;
        h.x=hp2(aA2.x,aA2.y); h.y=hp2(aA2.z,aA2.w); h.z=hp2(aA3.x,aA3.y); h.w=hp2(aA3.z,aA3.w);
        l.x=lp2(aA2.x,aA2.y); l.y=lp2(aA2.z,aA2.w); l.z=lp2(aA3.x,aA3.y); l.w=lp2(aA3.z,aA3.w);
        *(uint4*)&Ahi[buf][wbA1] = h; *(uint4*)&Alo[buf][wbA1] = l;
    };
    auto repack_B = [&](int buf) {
        uint4 h, l;
        h.x=hp2(aB0.x,aB0.y); h.y=hp2(aB0.z,aB0.w); h.z=hp2(aB1.x,aB1.y); h.w=hp2(aB1.z,aB1.w);
        l.x=lp2(aB0.x,aB0.y); l.y=lp2(aB0.z,aB0.w); l.z=lp2(aB1.x,aB1.y); l.w=lp2(aB1.z,aB1.w);
        *(uint4*)&Ahi[buf][wbA0] = h; *(uint4*)&Alo[buf][wbA0] = l;
        h.x=hp2(aB2.x,aB2.y); h.y=hp2(aB2.z,aB2.w); h.z=hp2(aB3.x,aB3.y); h.w=hp2(aB3.z,aB3.w);
        l.x=lp2(aB2.x,aB2.y); l.y=lp2(aB2.z,aB2.w); l.z=lp2(aB3.x,aB3.y); l.w=lp2(aB3.z,aB3.w);
        *(uint4*)&Ahi[buf][wbA1] = h; *(uint4*)&Alo[buf][wbA1] = l;
    };
    const uint4* wbase = wtf + ((size_t)(((mt*NKC)*4 + wn*2)*2))*64 + lane;

    short8v bhc[2], blc[2], bhn[2], bln[2];
    #pragma unroll
    for (int q = 0; q < 2; ++q) {
        bhc[q] = *(const short8v*)(wbase + q*128);
        blc[q] = *(const short8v*)(wbase + q*128 + 64);
    }
    loadA_B(0);
    repack_B(0);
    loadA_A(1);
    __syncthreads();
    int cur = 0;

    #define CONV_MFMA_BLOCK                                                            \
        _Pragma("unroll")                                                              \
        for (int p = 0; p < 4; ++p) {                                                  \
            int off = (wm*4 + p)*512 + l4*128 + l15*8;                                 \
            short8v ah = *(const short8v*)&Ahi[cur][off];                              \
            short8v al = *(const short8v*)&Alo[cur][off];                              \
            _Pragma("unroll")                                                          \
            for (int q = 0; q < 2; ++q) {                                              \
                acc[p][q] = __builtin_amdgcn_mfma_f32_16x16x32_bf16(ah, bhc[q], acc[p][q], 0, 0, 0); \
                acc[p][q] = __builtin_amdgcn_mfma_f32_16x16x32_bf16(ah, blc[q], acc[p][q], 0, 0, 0); \
                acc[p][q] = __builtin_amdgcn_mfma_f32_16x16x32_bf16(al, bhc[q], acc[p][q], 0, 0, 0); \
            }                                                                          \
        }

    for (int kc = 0; kc < NKC; kc += 2) {
        // even iter: B-frags for kc+1 FIRST (older), A-prefetch kc+2 SECOND (newer)
        {
            const uint4* wb = wbase + (size_t)(kc+1)*512;
            #pragma unroll
            for (int q = 0; q < 2; ++q) {
                bhn[q] = *(const short8v*)(wb + q*128);
                bln[q] = *(const short8v*)(wb + q*128 + 64);
            }
        }
        if (kc + 2 < NKC) loadA_B(kc + 2);
        CONV_MFMA_BLOCK
        repack_A(cur ^ 1);    // waits set-A (issued a full iteration ago); newer loads stay in flight
        #pragma unroll
        for (int q = 0; q < 2; ++q) { bhc[q] = bhn[q]; blc[q] = bln[q]; }   // waits bhn only
        __syncthreads();
        cur ^= 1;

        // odd iter
        int k1 = kc + 1;
        if (k1 + 1 < NKC) {
            const uint4* wb = wbase + (size_t)(k1+1)*512;
            #pragma unroll
            for (int q = 0; q < 2; ++q) {
                bhn[q] = *(const short8v*)(wb + q*128);
                bln[q] = *(const short8v*)(wb + q*128 + 64);
            }
        }
        if (k1 + 2 < NKC) loadA_A(k1 + 2);
        CONV_MFMA_BLOCK
        if (k1 + 1 < NKC) {
            repack_B(cur ^ 1);
            #pragma unroll
            for (int q = 0; q < 2; ++q) { bhc[q] = bhn[q]; blc[q] = bln[q]; }
        }
        __syncthreads();
        cur ^= 1;
    }
    #undef CONV_MFMA_BLOCK

    int bbk = n0 >> 10;
    int pos0 = (n0 & 1023) + wm*64;
    #pragma unroll
    for (int p = 0; p < 4; ++p) {
        int posb = pos0 + p*16 + l4*4;
        #pragma unroll
        for (int q = 0; q < 2; ++q) {
            int col = m0 + wn*32 + q*16 + l15;
            float bv = convb[col];
            uint4 o;
            o.x = pack_hl(acc[p][q][0] + bv);
            o.y = pack_hl(acc[p][q][1] + bv);
            o.z = pack_hl(acc[p][q][2] + bv);
            o.w = pack_hl(acc[p][q][3] + bv);
            *(uint4*)&ytp[((size_t)(bbk*NCO + col))*OHW + posb] = o;
        }
    }
}

// ---------------- generic split-bf16 MFMA GEMM ----------------
template<int MODE, int TM, int TN, int AF>
__launch_bounds__(256)
__global__ void gemm_pk(const void* __restrict__ Av, const unsigned* __restrict__ B,
                        float* __restrict__ C, int K, int N,
                        long sA, long sB, long sC,
                        const float* __restrict__ aux, unsigned* __restrict__ dmaxU) {
    constexpr int NA = TM/64, NBs = TN/64;
    constexpr int WSM = TM/64;
    constexpr int WSN = 4/WSM;
    constexpr int TWM = TM/WSM, TWN = TN/WSN;
    constexpr int P = TWM/16, Q = TWN/16;
    __shared__ __align__(16) unsigned short Ahi[TM*32], Alo[TM*32];
    __shared__ __align__(16) unsigned short Bhi[TN*32], Blo[TN*32];
    int z = blockIdx.z;
    const unsigned* Ab = (const unsigned*)Av + (size_t)z*sA;
    const unsigned* Bb = B + (size_t)z*sB;
    float* Cb = C + (size_t)z*sC;
    int n0 = blockIdx.x*TN, m0 = blockIdx.y*TM;
    int t = threadIdx.x;
    int lane = t & 63, wid = t >> 6;
    int wm = (WSM==2) ? (wid >> 1) : 0;
    int wn = (WSM==2) ? (wid & 1)  : wid;
    int l15 = lane & 15, l4 = lane >> 4;

    int rowA = t & (TM-1), kgA = t / TM;
    int rowB = t & (TN-1), kgB = t / TN;
    const unsigned* arow = Ab + (size_t)(m0 + rowA)*K + kgA*8;
    const unsigned* brw  = Bb + (size_t)(n0 + rowB)*K + kgB*8;
    int wbA = (rowA>>4)*512 + kgA*128 + (rowA&15)*8;
    int wbB = (rowB>>4)*512 + kgB*128 + (rowB&15)*8;

    float4v acc[P][Q] = {};
    uint4 ra[NA][2], rb[NBs][2];
    auto loadA = [&](int kc) {
        #pragma unroll
        for (int s = 0; s < NA; ++s) {
            const unsigned* p = arow + (size_t)kc*32 + s*16;
            ra[s][0] = *(const uint4*)p; ra[s][1] = *(const uint4*)(p + 4);
        }
    };
    auto loadB = [&](int kc) {
        #pragma unroll
        for (int s = 0; s < NBs; ++s) {
            const unsigned* p = brw + (size_t)kc*32 + s*16;
            rb[s][0] = *(const uint4*)p; rb[s][1] = *(const uint4*)(p + 4);
        }
    };
    loadA(0); loadB(0);
    int nkc = K >> 5;

    for (int kc = 0; kc < nkc; ++kc) {
        __syncthreads();
        uint4 h, l;
        #pragma unroll
        for (int s = 0; s < NA; ++s) {
            uint4 u0 = ra[s][0], u1 = ra[s][1];
            if (AF == 0) {
                h.x=hp2(u0.x,u0.y); h.y=hp2(u0.z,u0.w); h.z=hp2(u1.x,u1.y); h.w=hp2(u1.z,u1.w);
                l.x=lp2(u0.x,u0.y); l.y=lp2(u0.z,u0.w); l.z=lp2(u1.x,u1.y); l.w=lp2(u1.z,u1.w);
            } else {
                unsigned pk0 = pack_hl(__uint_as_float(u0.x)), pk1 = pack_hl(__uint_as_float(u0.y));
                unsigned pk2 = pack_hl(__uint_as_float(u0.z)), pk3 = pack_hl(__uint_as_float(u0.w));
                unsigned pk4 = pack_hl(__uint_as_float(u1.x)), pk5 = pack_hl(__uint_as_float(u1.y));
                unsigned pk6 = pack_hl(__uint_as_float(u1.z)), pk7 = pack_hl(__uint_as_float(u1.w));
                h.x = (pk0>>16) | (pk1 & 0xffff0000u); h.y = (pk2>>16) | (pk3 & 0xffff0000u);
                h.z = (pk4>>16) | (pk5 & 0xffff0000u); h.w = (pk6>>16) | (pk7 & 0xffff0000u);
                l.x = (pk0&0xffffu) | (pk1<<16); l.y = (pk2&0xffffu) | (pk3<<16);
                l.z = (pk4&0xffffu) | (pk5<<16); l.w = (pk6&0xffffu) | (pk7<<16);
            }
            *(uint4*)&Ahi[wbA + s*256] = h; *(uint4*)&Alo[wbA + s*256] = l;
        }
        #pragma unroll
        for (int s = 0; s < NBs; ++s) {
            uint4 u0 = rb[s][0], u1 = rb[s][1];
            h.x=hp2(u0.x,u0.y); h.y=hp2(u0.z,u0.w); h.z=hp2(u1.x,u1.y); h.w=hp2(u1.z,u1.w);
            l.x=lp2(u0.x,u0.y); l.y=lp2(u0.z,u0.w); l.z=lp2(u1.x,u1.y); l.w=lp2(u1.z,u1.w);
            *(uint4*)&Bhi[wbB + s*256] = h; *(uint4*)&Blo[wbB + s*256] = l;
        }
        __syncthreads();
        if (kc + 1 < nkc) { loadA(kc+1); loadB(kc+1); }

        short8v bh[Q], bl[Q];
        #pragma unroll
        for (int q = 0; q < Q; ++q) {
            int off = (wn*Q + q)*512 + l4*128 + l15*8;
            bh[q] = *(const short8v*)&Bhi[off];
            bl[q] = *(const short8v*)&Blo[off];
        }
        #pragma unroll
        for (int p = 0; p < P; ++p) {
            int off = (wm*P + p)*512 + l4*128 + l15*8;
            short8v ah = *(const short8v*)&Ahi[off];
            short8v al = *(const short8v*)&Alo[off];
            #pragma unroll
            for (int q = 0; q < Q; ++q) {
                acc[p][q] = __builtin_amdgcn_mfma_f32_16x16x32_bf16(ah, bh[q], acc[p][q], 0, 0, 0);
                acc[p][q] = __builtin_amdgcn_mfma_f32_16x16x32_bf16(ah, bl[q], acc[p][q], 0, 0, 0);
                acc[p][q] = __builtin_amdgcn_mfma_f32_16x16x32_bf16(al, bh[q], acc[p][q], 0, 0, 0);
            }
        }
    }

    if (MODE == 0) {
        #pragma unroll
        for (int p = 0; p < P; ++p) {
            int mb = m0 + wm*TWM + p*16 + l4*4;
            #pragma unroll
            for (int q = 0; q < Q; ++q) {
                int n = n0 + wn*TWN + q*16 + l15;
                #pragma unroll
                for (int r = 0; r < 4; ++r)
                    Cb[(size_t)(mb + r)*N + n] = acc[p][q][r];
            }
        }
    } else {
        const float inv = 1.0f / sqrtf(512.0f);
        const float* sqb = aux + (size_t)z*NTOK;
        float tmax = 0.f;
        #pragma unroll
        for (int p = 0; p < P; ++p) {
            int mb = m0 + wm*TWM + p*16 + l4*4;
            #pragma unroll
            for (int q = 0; q < Q; ++q) {
                int n = n0 + wn*TWN + q*16 + l15;
                float sn = sqb[n];
                #pragma unroll
                for (int r = 0; r < 4; ++r) {
                    float d2 = sqb[mb + r] + sn - 2.0f*acc[p][q][r];
                    float d = sqrtf(fmaxf(d2, 0.0f)) * inv;
                    Cb[(size_t)(mb + r)*N + n] = d;
                    tmax = fmaxf(tmax, d);
                }
            }
        }
        __shared__ float redm[4];
        #pragma unroll
        for (int off = 32; off; off >>= 1) tmax = fmaxf(tmax, __shfl_xor(tmax, off, 64));
        if (lane == 0) redm[wid] = tmax;
        __syncthreads();
        if (t == 0) {
            float m = fmaxf(fmaxf(redm[0], redm[1]), fmaxf(redm[2], redm[3]));
            atomicMax(dmaxU + z, __float_as_uint(m));
        }
    }
}

// ---------------- remaining pipeline ----------------
__global__ void wsum_rows(const float* __restrict__ amat, float* __restrict__ wsum) {
    int row = blockIdx.x*4 + (threadIdx.x >> 6);
    int lane = threadIdx.x & 63;
    const float* ar = amat + (size_t)row*OHW;
    float s = 0.f;
    #pragma unroll
    for (int r = 0; r < 16; ++r) s += ar[lane + 64*r];
    #pragma unroll
    for (int off = 32; off; off >>= 1) s += __shfl_xor(s, off, 64);
    if (lane == 0) wsum[row] = s;
}

__device__ __forceinline__ float block_sum256(float v, float* red) {
    #pragma unroll
    for (int off = 32; off; off >>= 1) v += __shfl_xor(v, off, 64);
    __syncthreads();
    if ((threadIdx.x & 63) == 0) red[threadIdx.x >> 6] = v;
    __syncthreads();
    return red[0] + red[1] + red[2] + red[3];
}

__global__ void ln_conf(const float* __restrict__ C2, const float* __restrict__ wsum,
                        const float* __restrict__ xskip, const float* __restrict__ g,
                        const float* __restrict__ be, const float* __restrict__ confw,
                        const float* __restrict__ confb, float* __restrict__ xtok,
                        unsigned* __restrict__ xtokpk,
                        float* __restrict__ wexp, float* __restrict__ sqv) {
    __shared__ float red[4];
    int row = blockIdx.x, t = threadIdx.x;
    float ws = wsum[row] + EPS;
    size_t base = (size_t)row*NCO;
    float v0 = C2[base + t]       / ws + xskip[base + t];
    float v1 = C2[base + t + 256] / ws + xskip[base + t + 256];
    float mu  = block_sum256(v0 + v1, red) / 512.0f;
    float d0 = v0 - mu, d1 = v1 - mu;
    float var = block_sum256(d0*d0 + d1*d1, red) / 512.0f;
    float sv = sqrtf(var + 1e-5f);
    float x0 = d0/sv * g[t]       + be[t];
    float x1 = d1/sv * g[t + 256] + be[t + 256];
    xtok[base + t] = x0;
    xtok[base + t + 256] = x1;
    xtokpk[base + t] = pack_hl(x0);
    xtokpk[base + t + 256] = pack_hl(x1);
    float cs = block_sum256(x0*confw[t] + x1*confw[t + 256], red);
    float qs = block_sum256(x0*x0 + x1*x1, red);
    if (t == 0) {
        wexp[row] = expf(cs + confb[0]);
        sqv[row]  = qs;
    }
}

__global__ void knn_dens(const float* __restrict__ dist, float* __restrict__ dens) {
    int row = blockIdx.x*4 + (threadIdx.x >> 6);
    int lane = threadIdx.x & 63;
    const float* dr = dist + (size_t)row*NTOK;
    float v0 = dr[lane], v1 = dr[lane+64], v2 = dr[lane+128], v3 = dr[lane+192];
    float acc = 0.f;
    #pragma unroll
    for (int it = 0; it < 5; ++it) {
        float lm = fminf(fminf(v0, v1), fminf(v2, v3));
        float gm = lm;
        #pragma unroll
        for (int off = 32; off; off >>= 1) gm = fminf(gm, __shfl_xor(gm, off, 64));
        acc += gm*gm;
        ull ball = __ballot(lm == gm);
        int first = __ffsll(ball) - 1;
        if (lane == first) {
            if      (v0 == gm) v0 = 1e30f;
            else if (v1 == gm) v1 = 1e30f;
            else if (v2 == gm) v2 = 1e30f;
            else               v3 = 1e30f;
        }
    }
    if (lane == 0) dens[row] = expf(-(acc/5.0f));
}

__global__ void parent_score(const float* __restrict__ dist, const float* __restrict__ dens,
                             const unsigned* __restrict__ dmaxU, float* __restrict__ score) {
    int row = blockIdx.x*4 + (threadIdx.x >> 6);
    int lane = threadIdx.x & 63;
    int b = row >> 8;
    float di = dens[row];
    float dm = __uint_as_float(dmaxU[b]);
    const float* dr = dist + (size_t)row*NTOK;
    const float* db = dens + (size_t)b*NTOK;
    float pd = dm;
    #pragma unroll
    for (int r = 0; r < 4; ++r) {
        int j = lane + 64*r;
        pd = fminf(pd, (db[j] > di) ? dr[j] : dm);
    }
    #pragma unroll
    for (int off = 32; off; off >>= 1) pd = fminf(pd, __shfl_xor(pd, off, 64));
    if (lane == 0) score[row] = pd * di;
}

__global__ void topk64(const float* __restrict__ score, int* __restrict__ ind) {
    int b = blockIdx.x, lane = threadIdx.x;
    const float* sb = score + b*NTOK;
    ull k0, k1, k2, k3;
    {
        unsigned i0 = lane, i1 = lane+64, i2 = lane+128, i3 = lane+192;
        k0 = ((ull)(__float_as_uint(sb[i0]) + 1u) << 32) | (unsigned)(4095 - i0);
        k1 = ((ull)(__float_as_uint(sb[i1]) + 1u) << 32) | (unsigned)(4095 - i1);
        k2 = ((ull)(__float_as_uint(sb[i2]) + 1u) << 32) | (unsigned)(4095 - i2);
        k3 = ((ull)(__float_as_uint(sb[i3]) + 1u) << 32) | (unsigned)(4095 - i3);
    }
    for (int it = 0; it < 64; ++it) {
        ull lm = k0;
        if (k1 > lm) lm = k1;
        if (k2 > lm) lm = k2;
        if (k3 > lm) lm = k3;
        ull gm = lm;
        #pragma unroll
        for (int off = 32; off; off >>= 1) {
            ull o = __shfl_xor(gm, off, 64);
            if (o > gm) gm = o;
        }
        if (lane == 0) ind[b*NS + it] = 4095 - (int)(gm & 0xffffffffull);
        if      (k0 == gm) k0 = 0;
        else if (k1 == gm) k1 = 0;
        else if (k2 == gm) k2 = 0;
        else if (k3 == gm) k3 = 0;
    }
}

__global__ void assign_k(const float* __restrict__ dist, const int* __restrict__ ind,
                         int* __restrict__ idxcl) {
    int row = blockIdx.x*4 + (threadIdx.x >> 6);
    int lane = threadIdx.x & 63;
    int b = row >> 8, i = row & 255;
    int center = ind[b*NS + lane];
    float d = dist[((size_t)(b*NTOK + center))*NTOK + i];
    ull key = ((ull)__float_as_uint(d) << 32) | (unsigned)lane;
    #pragma unroll
    for (int off = 32; off; off >>= 1) {
        ull o = __shfl_xor(key, off, 64);
        if (o < key) key = o;
    }
    if (lane == 0) idxcl[row] = (int)(key & 0xffffffffull);
}

// fused: center self-assign + allw accumulation (LDS) + normw. grid(NB), 256 thr.
__global__ void finalize_cl(const int* __restrict__ ind, const float* __restrict__ wexp,
                            int* __restrict__ idxcl, float* __restrict__ normw) {
    __shared__ float allwL[NS];
    int b = blockIdx.x, t = threadIdx.x;
    if (t < NS) {
        idxcl[b*NTOK + ind[b*NS + t]] = t;
        allwL[t] = 0.f;
    }
    __syncthreads();
    int cl = idxcl[b*NTOK + t];
    float we = wexp[b*NTOK + t];
    atomicAdd(&allwL[cl], we);
    __syncthreads();
    normw[b*NTOK + t] = we / (allwL[cl] + EPS);
}

__global__ void merge_k(const float* __restrict__ xtok, const int* __restrict__ idxcl,
                        const float* __restrict__ normw, float* __restrict__ xout) {
    int row = blockIdx.x, t = threadIdx.x;
    int b = row >> 8;
    int cl = idxcl[row];
    float nw = normw[row];
    float* o = xout + ((size_t)(b*NS + cl))*NCO;
    const float* xr = xtok + (size_t)row*NCO;
    atomicAdd(&o[t],       xr[t]       * nw);
    atomicAdd(&o[t + 256], xr[t + 256] * nw);
}

__global__ void out_idx_aw(const int* __restrict__ idxagg, const float* __restrict__ aggw,
                           const int* __restrict__ idxcl, const float* __restrict__ normw,
                           float* __restrict__ dout, float* __restrict__ awbuf,
                           unsigned* __restrict__ maxw) {
    __shared__ float red[4];
    int bp = blockIdx.x*256 + threadIdx.x;
    int b = bp >> 14;
    int tok = idxagg[bp];
    int cl = idxcl[b*NTOK + tok];
    dout[(size_t)NB*NS*NCO + bp] = (float)cl;
    float aw = aggw[bp] * normw[b*NTOK + tok];
    awbuf[bp] = aw;
    float m = aw;
    #pragma unroll
    for (int off = 32; off; off >>= 1) m = fmaxf(m, __shfl_xor(m, off, 64));
    if ((threadIdx.x & 63) == 0) red[threadIdx.x >> 6] = m;
    __syncthreads();
    if (threadIdx.x == 0) {
        float mm = fmaxf(fmaxf(red[0], red[1]), fmaxf(red[2], red[3]));
        atomicMax(&maxw[b], __float_as_uint(mm));
    }
}

__global__ void aw_final(const float* __restrict__ awbuf, const float* __restrict__ maxw,
                         float* __restrict__ dout) {
    int bp = blockIdx.x*256 + threadIdx.x;
    int b = bp >> 14;
    dout[(size_t)NB*NS*NCO + (size_t)NB*NP + bp] = awbuf[bp] / maxw[b];
}

// ---------------- launch ----------------
extern "C" void kernel_launch(void* const* d_in, const int* in_sizes, int n_in,
                              void* d_out, int out_size, void* d_ws, size_t ws_size,
                              hipStream_t stream) {
    const float* x      = (const float*)d_in[0];
    const float* loc    = (const float*)d_in[1];
    const int*   idxagg = (const int*)  d_in[2];
    const float* aggw   = (const float*)d_in[3];
    const float* convw  = (const float*)d_in[7];
    const float* convb  = (const float*)d_in[8];
    const float* skipw  = (const float*)d_in[9];
    const float* lng    = (const float*)d_in[10];
    const float* lnb    = (const float*)d_in[11];
    const float* confw  = (const float*)d_in[12];
    const float* confb  = (const float*)d_in[13];

    float* ws = (float*)d_ws;
    float* dout = (float*)d_out;

    (void)hipMemsetAsync(ws, 0, ZERO_END*sizeof(float), stream);
    (void)hipMemsetAsync(dout, 0, (size_t)NB*NS*NCO*sizeof(float), stream);

    hist<<<dim3(NB*NP/256), 256, 0, stream>>>(loc, idxagg, aggw,
                                              (int*)(ws + OFF_SUMS), ws + OFF_CNT, ws + OFF_AMAT);
    prep_pack<<<dim3(3328), 256, 0, stream>>>(x, (unsigned*)(ws + OFF_XTPK),
                                              (unsigned*)(ws + OFF_XPK),
                                              convw, (uint4*)(ws + OFF_WT),
                                              (const float4*)skipw, (uint4*)(ws + OFF_SKWT));

    map_gemm<<<dim3(1, 32, 8), 512, 0, stream>>>((const int*)(ws + OFF_SUMS),
                                                 (const unsigned*)(ws + OFF_XTPK),
                                                 ws + OFF_CNT,
                                                 (unsigned*)(ws + OFF_SUMS));

    conv_gemm<<<dim3(64, 8), 256, 0, stream>>>((const unsigned*)(ws + OFF_SUMS),
                                               (const uint4*)(ws + OFF_WT), convb,
                                               (unsigned*)(ws + OFF_Y));

    wsum_rows<<<dim3(NB*NTOK/4), 256, 0, stream>>>(ws + OFF_AMAT, ws + OFF_WSUM);
    gemm_pk<0,64,64,1><<<dim3(8, 4, 8), 256, 0, stream>>>((const void*)(ws + OFF_AMAT),
                                                  (const unsigned*)(ws + OFF_Y),
                                                  ws + OFF_C2, OHW, NCO,
                                                  (long)NTOK*OHW, (long)NCO*OHW, (long)NTOK*NCO,
                                                  nullptr, nullptr);
    gemm_pk<0,64,64,0><<<dim3(8, 32, 1), 256, 0, stream>>>((const void*)(ws + OFF_XPK),
                                                   (const unsigned*)(ws + OFF_SKWT),
                                                   ws + OFF_XSKIP, CIN, NCO, 0, 0, 0,
                                                   nullptr, nullptr);

    ln_conf<<<dim3(NB*NTOK), 256, 0, stream>>>(ws + OFF_C2, ws + OFF_WSUM, ws + OFF_XSKIP,
                                               lng, lnb, confw, confb,
                                               ws + OFF_XTOK, (unsigned*)(ws + OFF_XTOKPK),
                                               ws + OFF_WEXP, ws + OFF_SQ);

    gemm_pk<1,64,64,0><<<dim3(4, 4, 8), 256, 0, stream>>>((const void*)(ws + OFF_XTOKPK),
                                                  (const unsigned*)(ws + OFF_XTOKPK),
                                                  ws + OFF_DIST, NCO, NTOK,
                                                  (long)NTOK*NCO, (long)NTOK*NCO, (long)NTOK*NTOK,
                                                  ws + OFF_SQ, (unsigned*)(ws + OFF_DMAX));

    knn_dens<<<dim3(NB*NTOK/4), 256, 0, stream>>>(ws + OFF_DIST, ws + OFF_DENS);
    parent_score<<<dim3(NB*NTOK/4), 256, 0, stream>>>(ws + OFF_DIST, ws + OFF_DENS,
                                                      (const unsigned*)(ws + OFF_DMAX), ws + OFF_SCORE);
    topk64<<<dim3(NB), 64, 0, stream>>>(ws + OFF_SCORE, (int*)(ws + OFF_IND));
    assign_k<<<dim3(NB*NTOK/4), 256, 0, stream>>>(ws + OFF_DIST, (const int*)(ws + OFF_IND),
                                                  (int*)(ws + OFF_IDXCL));
    finalize_cl<<<dim3(NB), 256, 0, stream>>>((const int*)(ws + OFF_IND), ws + OFF_WEXP,
                                              (int*)(ws + OFF_IDXCL), ws + OFF_NORMW);

    merge_k<<<dim3(NB*NTOK), 256, 0, stream>>>(ws + OFF_XTOK, (const int*)(ws + OFF_IDXCL),
                                               ws + OFF_NORMW, dout);
    out_idx_aw<<<dim3(NB*NP/256), 256, 0, stream>>>(idxagg, aggw, (const int*)(ws + OFF_IDXCL),
                                                    ws + OFF_NORMW, dout, ws + OFF_AWBUF,
                                                    (unsigned*)(ws + OFF_MAXW));
    aw_final<<<dim3(NB*NP/256), 256, 0, stream>>>(ws + OFF_AWBUF, (const float*)(ws + OFF_MAXW), dout);
}